// Round 2
// baseline (486.070 us; speedup 1.0000x reference)
//
#include <hip/hip_runtime.h>
#include <math.h>

// GraphTransformerLayer on MI355X (gfx950).
// B=8, N=1024, D=512, H=8, Dh=64, F=2048.
// Round 2: attn_ctx barrier removal + K-split x2 (occupancy), attn_mean re-grid,
//          new attn_fin combine kernel.

using bf16_t = __bf16;
typedef __attribute__((__ext_vector_type__(8))) __bf16 bf16x8;
typedef __attribute__((__ext_vector_type__(4))) __bf16 bf16x4;
typedef __attribute__((__ext_vector_type__(4))) float  f32x4;

#define DEVI __device__ __forceinline__

DEVI f32x4 mfma16(bf16x8 a, bf16x8 b, f32x4 c) {
  return __builtin_amdgcn_mfma_f32_16x16x32_bf16(a, b, c, 0, 0, 0);
}

__constant__ const float kScale = 0.125f;   // 1/sqrt(64)
#define NEGC  (-1.0e9f)
#define EPSC  (1e-5f)

// ---------------- f32 -> bf16 convert (vector4) ----------------
__global__ __launch_bounds__(256) void k_cvt(const float* __restrict__ in,
                                             bf16_t* __restrict__ out, int n4) {
  int i = blockIdx.x * 256 + threadIdx.x;
  if (i < n4) {
    float4 v = ((const float4*)in)[i];
    bf16x4 o = { (__bf16)v.x, (__bf16)v.y, (__bf16)v.z, (__bf16)v.w };
    ((bf16x4*)out)[i] = o;
  }
}

// ---------------- adjm = mask ? adj : NEG ; rowmax of masked adj ----------------
__global__ __launch_bounds__(256) void k_prep(const float* __restrict__ adj,
                                              const int* __restrict__ msk,
                                              float* __restrict__ adjm,
                                              float* __restrict__ rowmax) {
  int row  = blockIdx.x * 4 + (threadIdx.x >> 6);
  int lane = threadIdx.x & 63;
  float m = -INFINITY;
  for (int i = 0; i < 16; i++) {
    int c = lane + 64 * i;
    size_t idx = (size_t)row * 1024 + c;
    float a = adj[idx];
    bool valid = (msk[idx] != 0);
    adjm[idx] = valid ? a : NEGC;
    if (valid) m = fmaxf(m, a);
  }
  for (int off = 1; off < 64; off <<= 1) m = fmaxf(m, __shfl_xor(m, off));
  if (lane == 0) rowmax[row] = m;
}

// ---------------- QKV projection GEMM: [8192x512] x W^T -> q,k,v [8192x512] ----------------
__global__ __launch_bounds__(256) void k_qkv(const bf16_t* __restrict__ xb,
                                             const bf16_t* __restrict__ wq,
                                             const bf16_t* __restrict__ wk,
                                             const bf16_t* __restrict__ wv,
                                             bf16_t* __restrict__ q,
                                             bf16_t* __restrict__ k,
                                             bf16_t* __restrict__ v) {
  int bid = blockIdx.x;
  int mb = bid / 12, nb = bid % 12;
  int tid = threadIdx.x, wid = tid >> 6, lane = tid & 63;
  int l16 = lane & 15, g = lane >> 4;
  int rbase = mb * 128 + (wid >> 1) * 64;
  int cbase = nb * 128 + (wid & 1) * 64;
  int which = cbase >> 9, e0 = cbase & 511;
  const bf16_t* W = (which == 0) ? wq : (which == 1) ? wk : wv;
  bf16_t* O = (which == 0) ? q : (which == 1) ? k : v;

  f32x4 acc[4][4];
#pragma unroll
  for (int m = 0; m < 4; m++)
#pragma unroll
    for (int n = 0; n < 4; n++) acc[m][n] = (f32x4){0.f, 0.f, 0.f, 0.f};

  const bf16_t* Ap = xb + (size_t)(rbase + l16) * 512 + 8 * g;
  const bf16_t* Bp = W + (size_t)(e0 + l16) * 512 + 8 * g;
  for (int k0 = 0; k0 < 512; k0 += 32) {
    bf16x8 af[4], bq[4];
#pragma unroll
    for (int m = 0; m < 4; m++) af[m] = *(const bf16x8*)(Ap + m * 16 * 512 + k0);
#pragma unroll
    for (int n = 0; n < 4; n++) bq[n] = *(const bf16x8*)(Bp + n * 16 * 512 + k0);
#pragma unroll
    for (int m = 0; m < 4; m++)
#pragma unroll
      for (int n = 0; n < 4; n++) acc[m][n] = mfma16(af[m], bq[n], acc[m][n]);
  }
#pragma unroll
  for (int m = 0; m < 4; m++)
#pragma unroll
    for (int n = 0; n < 4; n++)
#pragma unroll
      for (int j = 0; j < 4; j++) {
        int row = rbase + m * 16 + g * 4 + j;
        int col = e0 + n * 16 + l16;
        O[(size_t)row * 512 + col] = (__bf16)acc[m][n][j];
      }
}

// ---------------- v transpose: [B,N,H*64] -> vT [B,H,64,N] ----------------
__global__ __launch_bounds__(256) void k_vtrans(const bf16_t* __restrict__ v,
                                                bf16_t* __restrict__ vT) {
  int bid = blockIdx.x;
  int nt = bid & 15, h = (bid >> 4) & 7, b = bid >> 7;
  __shared__ bf16_t t[64 * 66];
  int tid = threadIdx.x, wid = tid >> 6, lane = tid & 63;
  for (int i = 0; i < 16; i++) {
    int n = wid * 16 + i;
    t[lane * 66 + n] = v[(size_t)(b * 1024 + nt * 64 + n) * 512 + h * 64 + lane];
  }
  __syncthreads();
  for (int i = 0; i < 16; i++) {
    int d = wid * 16 + i;
    vT[(size_t)((b * 8 + h) * 64 + d) * 1024 + nt * 64 + lane] = t[d * 66 + lane];
  }
}

// ---------------- max_n |k[b,h,n,:]| ----------------
__global__ __launch_bounds__(256) void k_knorm(const bf16_t* __restrict__ kk,
                                               float* __restrict__ kmax) {
  int bh = blockIdx.x;
  int b = bh >> 3, h = bh & 7;
  int tid = threadIdx.x;
  float mx = 0.f;
  for (int n = tid; n < 1024; n += 256) {
    const bf16_t* kp = kk + (size_t)(b * 1024 + n) * 512 + h * 64;
    float ss = 0.f;
#pragma unroll
    for (int vv = 0; vv < 8; vv++) {
      bf16x8 kv = *(const bf16x8*)(kp + vv * 8);
#pragma unroll
      for (int e = 0; e < 8; e++) { float f = (float)kv[e]; ss += f * f; }
    }
    mx = fmaxf(mx, ss);
  }
  for (int off = 1; off < 64; off <<= 1) mx = fmaxf(mx, __shfl_xor(mx, off));
  __shared__ float red[4];
  if ((tid & 63) == 0) red[tid >> 6] = mx;
  __syncthreads();
  if (tid == 0) kmax[bh] = sqrtf(fmaxf(fmaxf(red[0], red[1]), fmaxf(red[2], red[3])));
}

// ---------------- score upper bound C[b,h,n] = |q| * kmax / 8 + rowmax(adj) ----------------
__global__ __launch_bounds__(256) void k_cbound(const bf16_t* __restrict__ q,
                                                const float* __restrict__ kmax,
                                                const float* __restrict__ rowmax,
                                                float* __restrict__ Cb) {
  int t = blockIdx.x * 256 + threadIdx.x;  // (b*8+h)*1024 + n
  int b = t >> 13, h = (t >> 10) & 7, n = t & 1023;
  const bf16_t* qp = q + (size_t)(b * 1024 + n) * 512 + h * 64;
  float ss = 0.f;
#pragma unroll
  for (int vv = 0; vv < 8; vv++) {
    bf16x8 kv = *(const bf16x8*)(qp + vv * 8);
#pragma unroll
    for (int e = 0; e < 8; e++) { float f = (float)kv[e]; ss += f * f; }
  }
  float am = rowmax[n];
  Cb[t] = (am < -1e30f) ? 0.f : (sqrtf(ss) * kmax[b * 8 + h] * kScale + am);
}

// ---------------- attention partial: un-normalized ctx partial + partial l ----------------
// grid 2048: bid = split(1) | qt(4) | h(3) | b(3). Each block: 8 kt tiles of 64 k.
__global__ __launch_bounds__(256) void k_attn_ctx(const bf16_t* __restrict__ q,
                                                  const bf16_t* __restrict__ kk,
                                                  const bf16_t* __restrict__ vT,
                                                  const float* __restrict__ adjm,
                                                  const float* __restrict__ Cb,
                                                  float* __restrict__ lp,
                                                  bf16_t* __restrict__ ctxp0,
                                                  bf16_t* __restrict__ ctxp1) {
  __shared__ bf16_t pt[4][16 * 72];
  int bid = blockIdx.x;
  int split = bid & 1, qt = (bid >> 1) & 15, h = (bid >> 5) & 7, b = bid >> 8;
  int tid = threadIdx.x, wid = tid >> 6, lane = tid & 63;
  int l16 = lane & 15, g = lane >> 4;
  int qg0 = qt * 64 + wid * 16;
  bf16_t* ctxp = split ? ctxp1 : ctxp0;

  const bf16_t* qp = q + (size_t)(b * 1024 + qg0 + l16) * 512 + h * 64 + 8 * g;
  bf16x8 aq0 = *(const bf16x8*)qp;
  bf16x8 aq1 = *(const bf16x8*)(qp + 32);

  float Cj[4];
#pragma unroll
  for (int j = 0; j < 4; j++) Cj[j] = Cb[(b * 8 + h) * 1024 + qg0 + g * 4 + j];

  f32x4 cacc[4];
#pragma unroll
  for (int d = 0; d < 4; d++) cacc[d] = (f32x4){0.f, 0.f, 0.f, 0.f};
  float ls[4] = {0.f, 0.f, 0.f, 0.f};
  bf16_t* myp = pt[wid];  // wave-private LDS tile: NO barriers needed
  int kvbase = (b * 8 + h) * 64;

  for (int kt = split * 8; kt < split * 8 + 8; kt++) {
    int kc0 = kt * 64;
#pragma unroll
    for (int cg = 0; cg < 4; cg++) {
      const bf16_t* kp = kk + (size_t)(b * 1024 + kc0 + cg * 16 + l16) * 512 + h * 64 + 8 * g;
      f32x4 s = (f32x4){0.f, 0.f, 0.f, 0.f};
      s = mfma16(aq0, *(const bf16x8*)kp, s);
      s = mfma16(aq1, *(const bf16x8*)(kp + 32), s);
#pragma unroll
      for (int j = 0; j < 4; j++) {
        int qr = qg0 + g * 4 + j;
        int kc = kc0 + cg * 16 + l16;
        float sv = s[j] * kScale + adjm[(size_t)qr * 1024 + kc];
        float p = __expf(sv - Cj[j]);
        ls[j] += p;
        myp[(g * 4 + j) * 72 + cg * 16 + l16] = (__bf16)p;
      }
    }
#pragma unroll
    for (int half = 0; half < 2; half++) {
      bf16x8 pa = *(const bf16x8*)(myp + l16 * 72 + half * 32 + 8 * g);
#pragma unroll
      for (int dg = 0; dg < 4; dg++) {
        const bf16_t* vp = vT + (size_t)(kvbase + dg * 16 + l16) * 1024 + kc0 + half * 32 + 8 * g;
        cacc[dg] = mfma16(pa, *(const bf16x8*)vp, cacc[dg]);
      }
    }
  }

#pragma unroll
  for (int j = 0; j < 4; j++)
    for (int off = 1; off < 16; off <<= 1) ls[j] += __shfl_xor(ls[j], off);

#pragma unroll
  for (int dg = 0; dg < 4; dg++)
#pragma unroll
    for (int j = 0; j < 4; j++) {
      int row = qg0 + g * 4 + j;
      ctxp[(size_t)(b * 1024 + row) * 512 + h * 64 + dg * 16 + l16] = (__bf16)cacc[dg][j];
    }
  if (l16 == 0) {
#pragma unroll
    for (int j = 0; j < 4; j++)
      lp[split * 65536 + (b * 8 + h) * 1024 + qg0 + g * 4 + j] = ls[j];
  }
}

// ---------------- combine partials -> ctx bf16, rcpl ----------------
__global__ __launch_bounds__(256) void k_attn_fin(const bf16_t* __restrict__ ctxp0,
                                                  const bf16_t* __restrict__ ctxp1,
                                                  const float* __restrict__ lp,
                                                  bf16_t* __restrict__ ctx,
                                                  float* __restrict__ rcpl) {
  int t = blockIdx.x * 256 + threadIdx.x;  // 1048576 groups of 4 elems
  int col4 = t & 127, row = t >> 7;
  int b = row >> 10, qq = row & 1023, h = col4 >> 4;
  int li = (b * 8 + h) * 1024 + qq;
  float l = lp[li] + lp[65536 + li];
  float rc = (l > 0.f) ? (1.f / l) : 0.f;
  bf16x4 p0 = ((const bf16x4*)ctxp0)[t];
  bf16x4 p1 = ((const bf16x4*)ctxp1)[t];
  bf16x4 o;
#pragma unroll
  for (int i = 0; i < 4; i++) o[i] = (__bf16)(((float)p0[i] + (float)p1[i]) * rc);
  ((bf16x4*)ctx)[t] = o;
  if ((col4 & 15) == 0) rcpl[li] = rc;
}

// ---------------- attention mean over heads -> d_out[4.19M .. ] ----------------
// grid 2048: bid = kq(2) | qt(6) | b(3). Block: 16 q rows x 256 k cols, loop 8 heads.
__global__ __launch_bounds__(256) void k_attn_mean(const bf16_t* __restrict__ q,
                                                   const bf16_t* __restrict__ kk,
                                                   const float* __restrict__ adjm,
                                                   const float* __restrict__ Cb,
                                                   const float* __restrict__ rcpl,
                                                   float* __restrict__ mout) {
  int bid = blockIdx.x;
  int kq = bid & 3, qt = (bid >> 2) & 63, b = bid >> 8;
  int tid = threadIdx.x, wid = tid >> 6, lane = tid & 63;
  int l16 = lane & 15, g = lane >> 4;
  int qg0 = qt * 16;
  int kc0 = kq * 256 + wid * 64;

  float av[4][4];
#pragma unroll
  for (int cg = 0; cg < 4; cg++)
#pragma unroll
    for (int j = 0; j < 4; j++)
      av[cg][j] = adjm[(size_t)(qg0 + g * 4 + j) * 1024 + kc0 + cg * 16 + l16];

  f32x4 macc[4];
#pragma unroll
  for (int cg = 0; cg < 4; cg++) macc[cg] = (f32x4){0.f, 0.f, 0.f, 0.f};

  for (int h = 0; h < 8; h++) {
    const bf16_t* qp = q + (size_t)(b * 1024 + qg0 + l16) * 512 + h * 64 + 8 * g;
    bf16x8 aq0 = *(const bf16x8*)qp;
    bf16x8 aq1 = *(const bf16x8*)(qp + 32);
    float Cj[4], Rj[4];
#pragma unroll
    for (int j = 0; j < 4; j++) {
      int sidx = (b * 8 + h) * 1024 + qg0 + g * 4 + j;
      Cj[j] = Cb[sidx];
      Rj[j] = rcpl[sidx];
    }
#pragma unroll
    for (int cg = 0; cg < 4; cg++) {
      const bf16_t* kp = kk + (size_t)(b * 1024 + kc0 + cg * 16 + l16) * 512 + h * 64 + 8 * g;
      f32x4 s = (f32x4){0.f, 0.f, 0.f, 0.f};
      s = mfma16(aq0, *(const bf16x8*)kp, s);
      s = mfma16(aq1, *(const bf16x8*)(kp + 32), s);
      f32x4 m = macc[cg];
#pragma unroll
      for (int j = 0; j < 4; j++) {
        float sv = s[j] * kScale + av[cg][j];
        m[j] += __expf(sv - Cj[j]) * Rj[j];
      }
      macc[cg] = m;
    }
  }
#pragma unroll
  for (int cg = 0; cg < 4; cg++)
#pragma unroll
    for (int j = 0; j < 4; j++)
      mout[(size_t)(b * 1024 + qg0 + g * 4 + j) * 1024 + kc0 + cg * 16 + l16] =
          macc[cg][j] * 0.125f;
}

// ---------------- FFN1: relu(z @ W1^T + b1) -> [8192 x 2048] bf16 ----------------
__global__ __launch_bounds__(256) void k_ffn1(const bf16_t* __restrict__ zb,
                                              const bf16_t* __restrict__ w1,
                                              const float* __restrict__ b1,
                                              bf16_t* __restrict__ hb) {
  int bid = blockIdx.x;
  int mb = bid >> 4, nb = bid & 15;
  int tid = threadIdx.x, wid = tid >> 6, lane = tid & 63;
  int l16 = lane & 15, g = lane >> 4;
  int rbase = mb * 128 + (wid >> 1) * 64;
  int cbase = nb * 128 + (wid & 1) * 64;

  f32x4 acc[4][4];
#pragma unroll
  for (int m = 0; m < 4; m++)
#pragma unroll
    for (int n = 0; n < 4; n++) acc[m][n] = (f32x4){0.f, 0.f, 0.f, 0.f};

  const bf16_t* Ap = zb + (size_t)(rbase + l16) * 512 + 8 * g;
  const bf16_t* Bp = w1 + (size_t)(cbase + l16) * 512 + 8 * g;
  for (int k0 = 0; k0 < 512; k0 += 32) {
    bf16x8 af[4], bq[4];
#pragma unroll
    for (int m = 0; m < 4; m++) af[m] = *(const bf16x8*)(Ap + m * 16 * 512 + k0);
#pragma unroll
    for (int n = 0; n < 4; n++) bq[n] = *(const bf16x8*)(Bp + n * 16 * 512 + k0);
#pragma unroll
    for (int m = 0; m < 4; m++)
#pragma unroll
      for (int n = 0; n < 4; n++) acc[m][n] = mfma16(af[m], bq[n], acc[m][n]);
  }
#pragma unroll
  for (int n = 0; n < 4; n++) {
    int col = cbase + n * 16 + l16;
    float bv = b1[col];
#pragma unroll
    for (int m = 0; m < 4; m++)
#pragma unroll
      for (int j = 0; j < 4; j++) {
        int row = rbase + m * 16 + g * 4 + j;
        hb[(size_t)row * 2048 + col] = (__bf16)fmaxf(acc[m][n][j] + bv, 0.f);
      }
  }
}

// ---------------- GEMM (32 rows x 512 cols / block) + residual + LayerNorm ----------------
__global__ __launch_bounds__(256) void k_lngemm(const bf16_t* __restrict__ A,
                                                const bf16_t* __restrict__ W, int K,
                                                const float* __restrict__ resid,
                                                const float* __restrict__ bias,
                                                const float* __restrict__ gam,
                                                const float* __restrict__ bet,
                                                float* __restrict__ outf,
                                                bf16_t* __restrict__ outb) {
  __shared__ float sm[32 * 512];
  int bid = blockIdx.x;
  int r0 = bid * 32;
  int tid = threadIdx.x, wid = tid >> 6, lane = tid & 63;
  int l16 = lane & 15, g4 = lane >> 4;
  int cw = wid * 128;

  f32x4 acc[2][8];
#pragma unroll
  for (int m = 0; m < 2; m++)
#pragma unroll
    for (int n = 0; n < 8; n++) acc[m][n] = (f32x4){0.f, 0.f, 0.f, 0.f};

  const bf16_t* Ap = A + (size_t)(r0 + l16) * K + 8 * g4;
  const bf16_t* Bp = W + (size_t)(cw + l16) * K + 8 * g4;
  for (int k0 = 0; k0 < K; k0 += 32) {
    bf16x8 a0 = *(const bf16x8*)(Ap + k0);
    bf16x8 a1 = *(const bf16x8*)(Ap + (size_t)16 * K + k0);
    bf16x8 bq[8];
#pragma unroll
    for (int n = 0; n < 8; n++) bq[n] = *(const bf16x8*)(Bp + (size_t)n * 16 * K + k0);
#pragma unroll
    for (int n = 0; n < 8; n++) {
      acc[0][n] = mfma16(a0, bq[n], acc[0][n]);
      acc[1][n] = mfma16(a1, bq[n], acc[1][n]);
    }
  }

  bool has_bias = (bias != nullptr);
#pragma unroll
  for (int n = 0; n < 8; n++) {
    int c = cw + n * 16 + l16;
    float bv = has_bias ? bias[c] : 0.f;
#pragma unroll
    for (int m = 0; m < 2; m++)
#pragma unroll
      for (int j = 0; j < 4; j++) sm[(m * 16 + g4 * 4 + j) * 512 + c] = acc[m][n][j] + bv;
  }
  __syncthreads();
  for (int idx = tid; idx < 32 * 512; idx += 256) sm[idx] += resid[(size_t)r0 * 512 + idx];
  __syncthreads();

  // LayerNorm: wave handles 8 rows
  for (int rr = 0; rr < 8; rr++) {
    int row = wid * 8 + rr;
    float v[8];
    float s = 0.f;
#pragma unroll
    for (int i = 0; i < 8; i++) { v[i] = sm[row * 512 + lane + 64 * i]; s += v[i]; }
    for (int off = 1; off < 64; off <<= 1) s += __shfl_xor(s, off);
    float mu = s * (1.f / 512.f);
    float sq = 0.f;
#pragma unroll
    for (int i = 0; i < 8; i++) { float d = v[i] - mu; sq += d * d; }
    for (int off = 1; off < 64; off <<= 1) sq += __shfl_xor(sq, off);
    float rs = rsqrtf(sq * (1.f / 512.f) + EPSC);
#pragma unroll
    for (int i = 0; i < 8; i++) {
      int c = lane + 64 * i;
      float o = (v[i] - mu) * rs * gam[c] + bet[c];
      outf[(size_t)(r0 + row) * 512 + c] = o;
      if (outb) outb[(size_t)(r0 + row) * 512 + c] = (__bf16)o;
    }
  }
}

extern "C" void kernel_launch(void* const* d_in, const int* in_sizes, int n_in,
                              void* d_out, int out_size, void* d_ws, size_t ws_size,
                              hipStream_t stream) {
  (void)in_sizes; (void)n_in; (void)out_size; (void)ws_size;
  const float* x   = (const float*)d_in[0];
  const float* adj = (const float*)d_in[1];
  const int*   msk = (const int*)d_in[2];
  const float* Wq  = (const float*)d_in[3];
  const float* Wk  = (const float*)d_in[4];
  const float* Wv  = (const float*)d_in[5];
  const float* Wo  = (const float*)d_in[6];
  const float* W1  = (const float*)d_in[7];
  const float* b1  = (const float*)d_in[8];
  const float* W2  = (const float*)d_in[9];
  const float* b2  = (const float*)d_in[10];
  const float* g1  = (const float*)d_in[11];
  const float* be1 = (const float*)d_in[12];
  const float* g2  = (const float*)d_in[13];
  const float* be2 = (const float*)d_in[14];

  float* out  = (float*)d_out;
  float* mout = out + (size_t)8 * 1024 * 512;

  char* ws = (char*)d_ws;
  const size_t MB = 1024 * 1024;
  bf16_t* wqb = (bf16_t*)(ws);
  bf16_t* wkb = (bf16_t*)(ws + 512 * 1024);
  bf16_t* wvb = (bf16_t*)(ws + 1 * MB);
  bf16_t* wob = (bf16_t*)(ws + 3 * MB / 2);
  bf16_t* w1b = (bf16_t*)(ws + 2 * MB);
  bf16_t* w2b = (bf16_t*)(ws + 4 * MB);
  float*  Cb   = (float*)(ws + 6 * MB);              // 256 KB
  float*  rcpl = (float*)(ws + 6 * MB + 256 * 1024); // 256 KB
  float*  amax = (float*)(ws + 6 * MB + 512 * 1024); // 4 KB
  float*  kmax = (float*)(ws + 6 * MB + 768 * 1024); // 256 B
  float*  lp   = (float*)(ws + 7 * MB);              // 512 KB (2 splits x 64K f32)
  bf16_t* xb  = (bf16_t*)(ws + 8 * MB);    // 8 MB; reused as ctx after attention
  bf16_t* ctx = xb;
  bf16_t* qb  = (bf16_t*)(ws + 16 * MB);   // 8 MB
  bf16_t* kb  = (bf16_t*)(ws + 24 * MB);   // 8 MB
  bf16_t* vb  = (bf16_t*)(ws + 32 * MB);   // 8 MB (dead after vtrans)
  bf16_t* ctxp1 = vb;                      // 8 MB partial ctx split 1 (reuses vb)
  bf16_t* vT  = (bf16_t*)(ws + 40 * MB);   // 8 MB
  bf16_t* hb  = qb;                        // 32 MB, reuses q/k/ctxp1/vT after attention
  bf16_t* ctxp0 = (bf16_t*)(ws + 48 * MB); // 8 MB partial ctx split 0 (future zb)
  bf16_t* zb  = (bf16_t*)(ws + 48 * MB);   // 8 MB (written after fin consumed ctxp0)
  float*  zf  = (float*)(ws + 56 * MB);    // 16 MB
  float*  adjm = (float*)(ws + 72 * MB);   // 4 MB  (total 76 MB)

  // converts
  k_cvt<<<4096, 256, 0, stream>>>(x,  xb,  1048576);
  k_cvt<<<256,  256, 0, stream>>>(Wq, wqb, 65536);
  k_cvt<<<256,  256, 0, stream>>>(Wk, wkb, 65536);
  k_cvt<<<256,  256, 0, stream>>>(Wv, wvb, 65536);
  k_cvt<<<256,  256, 0, stream>>>(Wo, wob, 65536);
  k_cvt<<<1024, 256, 0, stream>>>(W1, w1b, 262144);
  k_cvt<<<1024, 256, 0, stream>>>(W2, w2b, 262144);

  k_prep<<<256, 256, 0, stream>>>(adj, msk, adjm, amax);

  k_qkv<<<768, 256, 0, stream>>>(xb, wqb, wkb, wvb, qb, kb, vb);
  k_vtrans<<<1024, 256, 0, stream>>>(vb, vT);
  k_knorm<<<64, 256, 0, stream>>>(kb, kmax);
  k_cbound<<<256, 256, 0, stream>>>(qb, kmax, amax, Cb);

  // attention: partials (k-split x2), combine, mean
  k_attn_ctx<<<2048, 256, 0, stream>>>(qb, kb, vT, adjm, Cb, lp, ctxp0, ctxp1);
  k_attn_fin<<<4096, 256, 0, stream>>>(ctxp0, ctxp1, lp, ctx, rcpl);
  k_attn_mean<<<2048, 256, 0, stream>>>(qb, kb, adjm, Cb, rcpl, mout);

  // Wo proj + residual + LN1 -> zf (f32) + zb (bf16)
  k_lngemm<<<256, 256, 0, stream>>>(ctx, wob, 512, x, nullptr, g1, be1, zf, zb);
  // FFN1
  k_ffn1<<<1024, 256, 0, stream>>>(zb, w1b, b1, hb);
  // FFN2 + b2 + residual(z) + LN2 -> out
  k_lngemm<<<256, 256, 0, stream>>>(hb, w2b, 2048, zf, b2, g2, be2, out, (bf16_t*)nullptr);
}

// Round 3
// 470.846 us; speedup vs baseline: 1.0323x; 1.0323x over previous
//
#include <hip/hip_runtime.h>
#include <math.h>
#include <stdint.h>

// GraphTransformerLayer on MI355X (gfx950).
// B=8, N=1024, D=512, H=8, Dh=64, F=2048.
// Round 3: attn_ctx -> double-buffered global_load_lds staging of K/vT tiles
//          (shared across waves) + XOR-swizzled LDS reads; lngemm -> 8-wave
//          register-resident LN (no 64KB LDS buffer).

using bf16_t = __bf16;
typedef __attribute__((__ext_vector_type__(8))) __bf16 bf16x8;
typedef __attribute__((__ext_vector_type__(4))) __bf16 bf16x4;
typedef __attribute__((__ext_vector_type__(4))) float  f32x4;

#define DEVI __device__ __forceinline__

DEVI f32x4 mfma16(bf16x8 a, bf16x8 b, f32x4 c) {
  return __builtin_amdgcn_mfma_f32_16x16x32_bf16(a, b, c, 0, 0, 0);
}

// async global->LDS, 16B per lane. dest = wave-uniform base (+ lane*16 by HW).
DEVI void gload_lds16(const void* g, void* l) {
  __builtin_amdgcn_global_load_lds(
      (const __attribute__((address_space(1))) uint32_t*)g,
      (__attribute__((address_space(3))) uint32_t*)l, 16, 0, 0);
}

__constant__ const float kScale = 0.125f;   // 1/sqrt(64)
#define NEGC  (-1.0e9f)
#define EPSC  (1e-5f)

// ---------------- f32 -> bf16 convert (vector4) ----------------
__global__ __launch_bounds__(256) void k_cvt(const float* __restrict__ in,
                                             bf16_t* __restrict__ out, int n4) {
  int i = blockIdx.x * 256 + threadIdx.x;
  if (i < n4) {
    float4 v = ((const float4*)in)[i];
    bf16x4 o = { (__bf16)v.x, (__bf16)v.y, (__bf16)v.z, (__bf16)v.w };
    ((bf16x4*)out)[i] = o;
  }
}

// ---------------- adjm = mask ? adj : NEG ; rowmax of masked adj ----------------
__global__ __launch_bounds__(256) void k_prep(const float* __restrict__ adj,
                                              const int* __restrict__ msk,
                                              float* __restrict__ adjm,
                                              float* __restrict__ rowmax) {
  int row  = blockIdx.x * 4 + (threadIdx.x >> 6);
  int lane = threadIdx.x & 63;
  float m = -INFINITY;
  for (int i = 0; i < 16; i++) {
    int c = lane + 64 * i;
    size_t idx = (size_t)row * 1024 + c;
    float a = adj[idx];
    bool valid = (msk[idx] != 0);
    adjm[idx] = valid ? a : NEGC;
    if (valid) m = fmaxf(m, a);
  }
  for (int off = 1; off < 64; off <<= 1) m = fmaxf(m, __shfl_xor(m, off));
  if (lane == 0) rowmax[row] = m;
}

// ---------------- QKV projection GEMM: [8192x512] x W^T -> q,k,v [8192x512] ----------------
__global__ __launch_bounds__(256) void k_qkv(const bf16_t* __restrict__ xb,
                                             const bf16_t* __restrict__ wq,
                                             const bf16_t* __restrict__ wk,
                                             const bf16_t* __restrict__ wv,
                                             bf16_t* __restrict__ q,
                                             bf16_t* __restrict__ k,
                                             bf16_t* __restrict__ v) {
  int bid = blockIdx.x;
  int mb = bid / 12, nb = bid % 12;
  int tid = threadIdx.x, wid = tid >> 6, lane = tid & 63;
  int l16 = lane & 15, g = lane >> 4;
  int rbase = mb * 128 + (wid >> 1) * 64;
  int cbase = nb * 128 + (wid & 1) * 64;
  int which = cbase >> 9, e0 = cbase & 511;
  const bf16_t* W = (which == 0) ? wq : (which == 1) ? wk : wv;
  bf16_t* O = (which == 0) ? q : (which == 1) ? k : v;

  f32x4 acc[4][4];
#pragma unroll
  for (int m = 0; m < 4; m++)
#pragma unroll
    for (int n = 0; n < 4; n++) acc[m][n] = (f32x4){0.f, 0.f, 0.f, 0.f};

  const bf16_t* Ap = xb + (size_t)(rbase + l16) * 512 + 8 * g;
  const bf16_t* Bp = W + (size_t)(e0 + l16) * 512 + 8 * g;
  for (int k0 = 0; k0 < 512; k0 += 32) {
    bf16x8 af[4], bq[4];
#pragma unroll
    for (int m = 0; m < 4; m++) af[m] = *(const bf16x8*)(Ap + m * 16 * 512 + k0);
#pragma unroll
    for (int n = 0; n < 4; n++) bq[n] = *(const bf16x8*)(Bp + n * 16 * 512 + k0);
#pragma unroll
    for (int m = 0; m < 4; m++)
#pragma unroll
      for (int n = 0; n < 4; n++) acc[m][n] = mfma16(af[m], bq[n], acc[m][n]);
  }
#pragma unroll
  for (int m = 0; m < 4; m++)
#pragma unroll
    for (int n = 0; n < 4; n++)
#pragma unroll
      for (int j = 0; j < 4; j++) {
        int row = rbase + m * 16 + g * 4 + j;
        int col = e0 + n * 16 + l16;
        O[(size_t)row * 512 + col] = (__bf16)acc[m][n][j];
      }
}

// ---------------- v transpose: [B,N,H*64] -> vT [B,H,64,N] ----------------
__global__ __launch_bounds__(256) void k_vtrans(const bf16_t* __restrict__ v,
                                                bf16_t* __restrict__ vT) {
  int bid = blockIdx.x;
  int nt = bid & 15, h = (bid >> 4) & 7, b = bid >> 7;
  __shared__ bf16_t t[64 * 66];
  int tid = threadIdx.x, wid = tid >> 6, lane = tid & 63;
  for (int i = 0; i < 16; i++) {
    int n = wid * 16 + i;
    t[lane * 66 + n] = v[(size_t)(b * 1024 + nt * 64 + n) * 512 + h * 64 + lane];
  }
  __syncthreads();
  for (int i = 0; i < 16; i++) {
    int d = wid * 16 + i;
    vT[(size_t)((b * 8 + h) * 64 + d) * 1024 + nt * 64 + lane] = t[d * 66 + lane];
  }
}

// ---------------- max_n |k[b,h,n,:]| ----------------
__global__ __launch_bounds__(256) void k_knorm(const bf16_t* __restrict__ kk,
                                               float* __restrict__ kmax) {
  int bh = blockIdx.x;
  int b = bh >> 3, h = bh & 7;
  int tid = threadIdx.x;
  float mx = 0.f;
  for (int n = tid; n < 1024; n += 256) {
    const bf16_t* kp = kk + (size_t)(b * 1024 + n) * 512 + h * 64;
    float ss = 0.f;
#pragma unroll
    for (int vv = 0; vv < 8; vv++) {
      bf16x8 kv = *(const bf16x8*)(kp + vv * 8);
#pragma unroll
      for (int e = 0; e < 8; e++) { float f = (float)kv[e]; ss += f * f; }
    }
    mx = fmaxf(mx, ss);
  }
  for (int off = 1; off < 64; off <<= 1) mx = fmaxf(mx, __shfl_xor(mx, off));
  __shared__ float red[4];
  if ((tid & 63) == 0) red[tid >> 6] = mx;
  __syncthreads();
  if (tid == 0) kmax[bh] = sqrtf(fmaxf(fmaxf(red[0], red[1]), fmaxf(red[2], red[3])));
}

// ---------------- score upper bound C[b,h,n] = |q| * kmax / 8 + rowmax(adj) ----------------
__global__ __launch_bounds__(256) void k_cbound(const bf16_t* __restrict__ q,
                                                const float* __restrict__ kmax,
                                                const float* __restrict__ rowmax,
                                                float* __restrict__ Cb) {
  int t = blockIdx.x * 256 + threadIdx.x;  // (b*8+h)*1024 + n
  int b = t >> 13, h = (t >> 10) & 7, n = t & 1023;
  const bf16_t* qp = q + (size_t)(b * 1024 + n) * 512 + h * 64;
  float ss = 0.f;
#pragma unroll
  for (int vv = 0; vv < 8; vv++) {
    bf16x8 kv = *(const bf16x8*)(qp + vv * 8);
#pragma unroll
    for (int e = 0; e < 8; e++) { float f = (float)kv[e]; ss += f * f; }
  }
  float am = rowmax[n];
  Cb[t] = (am < -1e30f) ? 0.f : (sqrtf(ss) * kmax[b * 8 + h] * kScale + am);
}

// ---------------- attention partial: un-normalized ctx partial + partial l ----------------
// grid 2048: bid = split(1) | qt(4) | h(3) | b(3). Each block: 8 kt tiles of 64 k.
// K/vT tiles (8KB each) staged via global_load_lds, double-buffered, XOR-swizzled.
__global__ __launch_bounds__(256) void k_attn_ctx(const bf16_t* __restrict__ q,
                                                  const bf16_t* __restrict__ kk,
                                                  const bf16_t* __restrict__ vT,
                                                  const float* __restrict__ adjm,
                                                  const float* __restrict__ Cb,
                                                  float* __restrict__ lp,
                                                  bf16_t* __restrict__ ctxp0,
                                                  bf16_t* __restrict__ ctxp1) {
  __shared__ bf16_t ldsK[2][4096];      // 2 x 8KB : K tile  [64 k-rows][64 dh], swizzled
  __shared__ bf16_t ldsV[2][4096];      // 2 x 8KB : vT tile [64 d-rows][64 k],  swizzled
  __shared__ bf16_t pt[4][16 * 72];     // per-wave p tiles
  int bid = blockIdx.x;
  int split = bid & 1, qt = (bid >> 1) & 15, h = (bid >> 5) & 7, b = bid >> 8;
  int tid = threadIdx.x, wid = tid >> 6, lane = tid & 63;
  int l16 = lane & 15, g = lane >> 4;
  int qg0 = qt * 64 + wid * 16;
  bf16_t* ctxp = split ? ctxp1 : ctxp0;
  int kvbase = (b * 8 + h) * 64;

  // staging geometry: wave w stages bytes [w*2048, w*2048+2048) of each 8KB tile
  // dest byte d -> row = d>>7, stored colblk' = (d>>4)&7 ; source colblk = colblk' ^ (row&7)
  int d0 = wid * 2048 + lane * 16;
  int row0 = d0 >> 7, row1 = (d0 + 1024) >> 7;
  int cb0 = ((d0 >> 4) & 7) ^ (row0 & 7);
  int cb1 = ((d0 >> 4) & 7) ^ (row1 & 7);   // (d0+1024)>>4 & 7 == (d0>>4)&7
  const bf16_t* ksrc = kk + (size_t)(b * 1024) * 512 + h * 64;
  const bf16_t* vsrc = vT + (size_t)kvbase * 1024;

  auto stage = [&](int buf, int kc0) {
    gload_lds16(ksrc + (size_t)(kc0 + row0) * 512 + cb0 * 8, &ldsK[buf][wid * 1024]);
    gload_lds16(ksrc + (size_t)(kc0 + row1) * 512 + cb1 * 8, &ldsK[buf][wid * 1024 + 512]);
    gload_lds16(vsrc + (size_t)row0 * 1024 + kc0 + cb0 * 8, &ldsV[buf][wid * 1024]);
    gload_lds16(vsrc + (size_t)row1 * 1024 + kc0 + cb1 * 8, &ldsV[buf][wid * 1024 + 512]);
  };

  const bf16_t* qp = q + (size_t)(b * 1024 + qg0 + l16) * 512 + h * 64 + 8 * g;
  bf16x8 aq0 = *(const bf16x8*)qp;
  bf16x8 aq1 = *(const bf16x8*)(qp + 32);

  float Cj[4];
#pragma unroll
  for (int j = 0; j < 4; j++) Cj[j] = Cb[(b * 8 + h) * 1024 + qg0 + g * 4 + j];

  f32x4 cacc[4];
#pragma unroll
  for (int d = 0; d < 4; d++) cacc[d] = (f32x4){0.f, 0.f, 0.f, 0.f};
  float ls[4] = {0.f, 0.f, 0.f, 0.f};
  bf16_t* myp = pt[wid];  // wave-private
  int rph = l16 & 7;

  int ktS = split * 8, ktE = ktS + 8;
  stage(0, ktS * 64);
  __syncthreads();

  for (int kt = ktS; kt < ktE; ++kt) {
    int buf = (kt - ktS) & 1;
    int kc0 = kt * 64;
    int ktn = (kt + 1 < ktE) ? kt + 1 : kt;
    stage(buf ^ 1, ktn * 64);            // prefetch next tile (drains under compute)

    float am[4][4];                       // adjm for this tile, issued early
#pragma unroll
    for (int cg = 0; cg < 4; cg++)
#pragma unroll
      for (int j = 0; j < 4; j++)
        am[cg][j] = adjm[(size_t)(qg0 + g * 4 + j) * 1024 + kc0 + cg * 16 + l16];

    const char* curK = (const char*)ldsK[buf];
    const char* curV = (const char*)ldsV[buf];

#pragma unroll
    for (int cg = 0; cg < 4; cg++) {
      const char* krow = curK + ((cg * 16 + l16) << 7);
      bf16x8 k0 = *(const bf16x8*)(krow + ((g ^ rph) << 4));
      bf16x8 k1 = *(const bf16x8*)(krow + (((g + 4) ^ rph) << 4));
      f32x4 s = (f32x4){0.f, 0.f, 0.f, 0.f};
      s = mfma16(aq0, k0, s);
      s = mfma16(aq1, k1, s);
#pragma unroll
      for (int j = 0; j < 4; j++) {
        float sv = s[j] * kScale + am[cg][j];
        float p = __expf(sv - Cj[j]);
        ls[j] += p;
        myp[(g * 4 + j) * 72 + cg * 16 + l16] = (__bf16)p;
      }
    }
#pragma unroll
    for (int half = 0; half < 2; half++) {
      bf16x8 pa = *(const bf16x8*)(myp + l16 * 72 + half * 32 + 8 * g);
#pragma unroll
      for (int dg = 0; dg < 4; dg++) {
        const char* vrow = curV + ((dg * 16 + l16) << 7);
        bf16x8 vv = *(const bf16x8*)(vrow + (((g + half * 4) ^ rph) << 4));
        cacc[dg] = mfma16(pa, vv, cacc[dg]);
      }
    }
    __syncthreads();   // staged next tile complete; all waves done with buf
  }

#pragma unroll
  for (int j = 0; j < 4; j++)
    for (int off = 1; off < 16; off <<= 1) ls[j] += __shfl_xor(ls[j], off);

#pragma unroll
  for (int dg = 0; dg < 4; dg++)
#pragma unroll
    for (int j = 0; j < 4; j++) {
      int row = qg0 + g * 4 + j;
      ctxp[(size_t)(b * 1024 + row) * 512 + h * 64 + dg * 16 + l16] = (__bf16)cacc[dg][j];
    }
  if (l16 == 0) {
#pragma unroll
    for (int j = 0; j < 4; j++)
      lp[split * 65536 + (b * 8 + h) * 1024 + qg0 + g * 4 + j] = ls[j];
  }
}

// ---------------- combine partials -> ctx bf16, rcpl ----------------
__global__ __launch_bounds__(256) void k_attn_fin(const bf16_t* __restrict__ ctxp0,
                                                  const bf16_t* __restrict__ ctxp1,
                                                  const float* __restrict__ lp,
                                                  bf16_t* __restrict__ ctx,
                                                  float* __restrict__ rcpl) {
  int t = blockIdx.x * 256 + threadIdx.x;  // 1048576 groups of 4 elems
  int col4 = t & 127, row = t >> 7;
  int b = row >> 10, qq = row & 1023, h = col4 >> 4;
  int li = (b * 8 + h) * 1024 + qq;
  float l = lp[li] + lp[65536 + li];
  float rc = (l > 0.f) ? (1.f / l) : 0.f;
  bf16x4 p0 = ((const bf16x4*)ctxp0)[t];
  bf16x4 p1 = ((const bf16x4*)ctxp1)[t];
  bf16x4 o;
#pragma unroll
  for (int i = 0; i < 4; i++) o[i] = (__bf16)(((float)p0[i] + (float)p1[i]) * rc);
  ((bf16x4*)ctx)[t] = o;
  if ((col4 & 15) == 0) rcpl[li] = rc;
}

// ---------------- attention mean over heads -> d_out[4.19M .. ] ----------------
// grid 2048: bid = kq(2) | qt(6) | b(3). Block: 16 q rows x 256 k cols, loop 8 heads.
__global__ __launch_bounds__(256) void k_attn_mean(const bf16_t* __restrict__ q,
                                                   const bf16_t* __restrict__ kk,
                                                   const float* __restrict__ adjm,
                                                   const float* __restrict__ Cb,
                                                   const float* __restrict__ rcpl,
                                                   float* __restrict__ mout) {
  int bid = blockIdx.x;
  int kq = bid & 3, qt = (bid >> 2) & 63, b = bid >> 8;
  int tid = threadIdx.x, wid = tid >> 6, lane = tid & 63;
  int l16 = lane & 15, g = lane >> 4;
  int qg0 = qt * 16;
  int kc0 = kq * 256 + wid * 64;

  float av[4][4];
#pragma unroll
  for (int cg = 0; cg < 4; cg++)
#pragma unroll
    for (int j = 0; j < 4; j++)
      av[cg][j] = adjm[(size_t)(qg0 + g * 4 + j) * 1024 + kc0 + cg * 16 + l16];

  f32x4 macc[4];
#pragma unroll
  for (int cg = 0; cg < 4; cg++) macc[cg] = (f32x4){0.f, 0.f, 0.f, 0.f};

  for (int h = 0; h < 8; h++) {
    const bf16_t* qp = q + (size_t)(b * 1024 + qg0 + l16) * 512 + h * 64 + 8 * g;
    bf16x8 aq0 = *(const bf16x8*)qp;
    bf16x8 aq1 = *(const bf16x8*)(qp + 32);
    float Cj[4], Rj[4];
#pragma unroll
    for (int j = 0; j < 4; j++) {
      int sidx = (b * 8 + h) * 1024 + qg0 + g * 4 + j;
      Cj[j] = Cb[sidx];
      Rj[j] = rcpl[sidx];
    }
#pragma unroll
    for (int cg = 0; cg < 4; cg++) {
      const bf16_t* kp = kk + (size_t)(b * 1024 + kc0 + cg * 16 + l16) * 512 + h * 64 + 8 * g;
      f32x4 s = (f32x4){0.f, 0.f, 0.f, 0.f};
      s = mfma16(aq0, *(const bf16x8*)kp, s);
      s = mfma16(aq1, *(const bf16x8*)(kp + 32), s);
      f32x4 m = macc[cg];
#pragma unroll
      for (int j = 0; j < 4; j++) {
        float sv = s[j] * kScale + av[cg][j];
        m[j] += __expf(sv - Cj[j]) * Rj[j];
      }
      macc[cg] = m;
    }
  }
#pragma unroll
  for (int cg = 0; cg < 4; cg++)
#pragma unroll
    for (int j = 0; j < 4; j++)
      mout[(size_t)(b * 1024 + qg0 + g * 4 + j) * 1024 + kc0 + cg * 16 + l16] =
          macc[cg][j] * 0.125f;
}

// ---------------- FFN1: relu(z @ W1^T + b1) -> [8192 x 2048] bf16 ----------------
__global__ __launch_bounds__(256) void k_ffn1(const bf16_t* __restrict__ zb,
                                              const bf16_t* __restrict__ w1,
                                              const float* __restrict__ b1,
                                              bf16_t* __restrict__ hb) {
  int bid = blockIdx.x;
  int mb = bid >> 4, nb = bid & 15;
  int tid = threadIdx.x, wid = tid >> 6, lane = tid & 63;
  int l16 = lane & 15, g = lane >> 4;
  int rbase = mb * 128 + (wid >> 1) * 64;
  int cbase = nb * 128 + (wid & 1) * 64;

  f32x4 acc[4][4];
#pragma unroll
  for (int m = 0; m < 4; m++)
#pragma unroll
    for (int n = 0; n < 4; n++) acc[m][n] = (f32x4){0.f, 0.f, 0.f, 0.f};

  const bf16_t* Ap = zb + (size_t)(rbase + l16) * 512 + 8 * g;
  const bf16_t* Bp = w1 + (size_t)(cbase + l16) * 512 + 8 * g;
  for (int k0 = 0; k0 < 512; k0 += 32) {
    bf16x8 af[4], bq[4];
#pragma unroll
    for (int m = 0; m < 4; m++) af[m] = *(const bf16x8*)(Ap + m * 16 * 512 + k0);
#pragma unroll
    for (int n = 0; n < 4; n++) bq[n] = *(const bf16x8*)(Bp + n * 16 * 512 + k0);
#pragma unroll
    for (int m = 0; m < 4; m++)
#pragma unroll
      for (int n = 0; n < 4; n++) acc[m][n] = mfma16(af[m], bq[n], acc[m][n]);
  }
#pragma unroll
  for (int n = 0; n < 4; n++) {
    int col = cbase + n * 16 + l16;
    float bv = b1[col];
#pragma unroll
    for (int m = 0; m < 4; m++)
#pragma unroll
      for (int j = 0; j < 4; j++) {
        int row = rbase + m * 16 + g * 4 + j;
        hb[(size_t)row * 2048 + col] = (__bf16)fmaxf(acc[m][n][j] + bv, 0.f);
      }
  }
}

// ---------------- GEMM (32 rows x 512 cols / block, 8 waves) + residual + LayerNorm ----------------
// wave = 16 rows (wid>>2) x 128 cols (wid&3); acc in regs; LN via butterfly + small LDS.
__global__ __launch_bounds__(512) void k_lngemm(const bf16_t* __restrict__ A,
                                                const bf16_t* __restrict__ W, int K,
                                                const float* __restrict__ resid,
                                                const float* __restrict__ bias,
                                                const float* __restrict__ gam,
                                                const float* __restrict__ bet,
                                                float* __restrict__ outf,
                                                bf16_t* __restrict__ outb) {
  __shared__ float redS[2][4][16];
  __shared__ float redQ[2][4][16];
  int r0 = blockIdx.x * 32;
  int tid = threadIdx.x, wid = tid >> 6, lane = tid & 63;
  int l16 = lane & 15, g4 = lane >> 4;
  int rw = (wid >> 2) * 16;       // row-half offset
  int cw = (wid & 3) * 128;       // col base

  f32x4 acc[8];
#pragma unroll
  for (int n = 0; n < 8; n++) acc[n] = (f32x4){0.f, 0.f, 0.f, 0.f};

  const bf16_t* Ap = A + (size_t)(r0 + rw + l16) * K + 8 * g4;
  const bf16_t* Bp = W + (size_t)(cw + l16) * K + 8 * g4;
  for (int k0 = 0; k0 < K; k0 += 32) {
    bf16x8 a0 = *(const bf16x8*)(Ap + k0);
    bf16x8 bq[8];
#pragma unroll
    for (int n = 0; n < 8; n++) bq[n] = *(const bf16x8*)(Bp + (size_t)n * 16 * K + k0);
#pragma unroll
    for (int n = 0; n < 8; n++) acc[n] = mfma16(a0, bq[n], acc[n]);
  }

  // val = acc + bias + resid ; per-row partial sums
  bool has_bias = (bias != nullptr);
  float val[8][4];
  float vsum[4] = {0.f, 0.f, 0.f, 0.f}, vsq[4] = {0.f, 0.f, 0.f, 0.f};
#pragma unroll
  for (int n = 0; n < 8; n++) {
    int c = cw + n * 16 + l16;
    float bv = has_bias ? bias[c] : 0.f;
#pragma unroll
    for (int j = 0; j < 4; j++) {
      int row = r0 + rw + g4 * 4 + j;
      float v = acc[n][j] + bv + resid[(size_t)row * 512 + c];
      val[n][j] = v;
      vsum[j] += v;
      vsq[j]  += v * v;
    }
  }
#pragma unroll
  for (int j = 0; j < 4; j++)
    for (int off = 1; off < 16; off <<= 1) {
      vsum[j] += __shfl_xor(vsum[j], off);
      vsq[j]  += __shfl_xor(vsq[j], off);
    }
  if (l16 == 0) {
#pragma unroll
    for (int j = 0; j < 4; j++) {
      redS[wid >> 2][wid & 3][g4 * 4 + j] = vsum[j];
      redQ[wid >> 2][wid & 3][g4 * 4 + j] = vsq[j];
    }
  }
  __syncthreads();

  float mu[4], rs[4];
#pragma unroll
  for (int j = 0; j < 4; j++) {
    int r = g4 * 4 + j, rh = wid >> 2;
    float s = redS[rh][0][r] + redS[rh][1][r] + redS[rh][2][r] + redS[rh][3][r];
    float qq = redQ[rh][0][r] + redQ[rh][1][r] + redQ[rh][2][r] + redQ[rh][3][r];
    mu[j] = s * (1.f / 512.f);
    float var = qq * (1.f / 512.f) - mu[j] * mu[j];
    rs[j] = rsqrtf(var + EPSC);
  }
#pragma unroll
  for (int n = 0; n < 8; n++) {
    int c = cw + n * 16 + l16;
    float gv = gam[c], bv = bet[c];
#pragma unroll
    for (int j = 0; j < 4; j++) {
      int row = r0 + rw + g4 * 4 + j;
      float o = (val[n][j] - mu[j]) * rs[j] * gv + bv;
      outf[(size_t)row * 512 + c] = o;
      if (outb) outb[(size_t)row * 512 + c] = (__bf16)o;
    }
  }
}

extern "C" void kernel_launch(void* const* d_in, const int* in_sizes, int n_in,
                              void* d_out, int out_size, void* d_ws, size_t ws_size,
                              hipStream_t stream) {
  (void)in_sizes; (void)n_in; (void)out_size; (void)ws_size;
  const float* x   = (const float*)d_in[0];
  const float* adj = (const float*)d_in[1];
  const int*   msk = (const int*)d_in[2];
  const float* Wq  = (const float*)d_in[3];
  const float* Wk  = (const float*)d_in[4];
  const float* Wv  = (const float*)d_in[5];
  const float* Wo  = (const float*)d_in[6];
  const float* W1  = (const float*)d_in[7];
  const float* b1  = (const float*)d_in[8];
  const float* W2  = (const float*)d_in[9];
  const float* b2  = (const float*)d_in[10];
  const float* g1  = (const float*)d_in[11];
  const float* be1 = (const float*)d_in[12];
  const float* g2  = (const float*)d_in[13];
  const float* be2 = (const float*)d_in[14];

  float* out  = (float*)d_out;
  float* mout = out + (size_t)8 * 1024 * 512;

  char* ws = (char*)d_ws;
  const size_t MB = 1024 * 1024;
  bf16_t* wqb = (bf16_t*)(ws);
  bf16_t* wkb = (bf16_t*)(ws + 512 * 1024);
  bf16_t* wvb = (bf16_t*)(ws + 1 * MB);
  bf16_t* wob = (bf16_t*)(ws + 3 * MB / 2);
  bf16_t* w1b = (bf16_t*)(ws + 2 * MB);
  bf16_t* w2b = (bf16_t*)(ws + 4 * MB);
  float*  Cb   = (float*)(ws + 6 * MB);              // 256 KB
  float*  rcpl = (float*)(ws + 6 * MB + 256 * 1024); // 256 KB
  float*  amax = (float*)(ws + 6 * MB + 512 * 1024); // 4 KB
  float*  kmax = (float*)(ws + 6 * MB + 768 * 1024); // 256 B
  float*  lp   = (float*)(ws + 7 * MB);              // 512 KB (2 splits x 64K f32)
  bf16_t* xb  = (bf16_t*)(ws + 8 * MB);    // 8 MB; reused as ctx after attention
  bf16_t* ctx = xb;
  bf16_t* qb  = (bf16_t*)(ws + 16 * MB);   // 8 MB
  bf16_t* kb  = (bf16_t*)(ws + 24 * MB);   // 8 MB
  bf16_t* vb  = (bf16_t*)(ws + 32 * MB);   // 8 MB (dead after vtrans)
  bf16_t* ctxp1 = vb;                      // 8 MB partial ctx split 1 (reuses vb)
  bf16_t* vT  = (bf16_t*)(ws + 40 * MB);   // 8 MB
  bf16_t* hb  = qb;                        // 32 MB, reuses q/k/ctxp1/vT after attention
  bf16_t* ctxp0 = (bf16_t*)(ws + 48 * MB); // 8 MB partial ctx split 0 (future zb)
  bf16_t* zb  = (bf16_t*)(ws + 48 * MB);   // 8 MB (written after fin consumed ctxp0)
  float*  zf  = (float*)(ws + 56 * MB);    // 16 MB
  float*  adjm = (float*)(ws + 72 * MB);   // 4 MB  (total 76 MB)

  // converts
  k_cvt<<<4096, 256, 0, stream>>>(x,  xb,  1048576);
  k_cvt<<<256,  256, 0, stream>>>(Wq, wqb, 65536);
  k_cvt<<<256,  256, 0, stream>>>(Wk, wkb, 65536);
  k_cvt<<<256,  256, 0, stream>>>(Wv, wvb, 65536);
  k_cvt<<<256,  256, 0, stream>>>(Wo, wob, 65536);
  k_cvt<<<1024, 256, 0, stream>>>(W1, w1b, 262144);
  k_cvt<<<1024, 256, 0, stream>>>(W2, w2b, 262144);

  k_prep<<<256, 256, 0, stream>>>(adj, msk, adjm, amax);

  k_qkv<<<768, 256, 0, stream>>>(xb, wqb, wkb, wvb, qb, kb, vb);
  k_vtrans<<<1024, 256, 0, stream>>>(vb, vT);
  k_knorm<<<64, 256, 0, stream>>>(kb, kmax);
  k_cbound<<<256, 256, 0, stream>>>(qb, kmax, amax, Cb);

  // attention: partials (k-split x2), combine, mean
  k_attn_ctx<<<2048, 256, 0, stream>>>(qb, kb, vT, adjm, Cb, lp, ctxp0, ctxp1);
  k_attn_fin<<<4096, 256, 0, stream>>>(ctxp0, ctxp1, lp, ctx, rcpl);
  k_attn_mean<<<2048, 256, 0, stream>>>(qb, kb, adjm, Cb, rcpl, mout);

  // Wo proj + residual + LN1 -> zf (f32) + zb (bf16)
  k_lngemm<<<256, 512, 0, stream>>>(ctx, wob, 512, x, nullptr, g1, be1, zf, zb);
  // FFN1
  k_ffn1<<<1024, 256, 0, stream>>>(zb, w1b, b1, hb);
  // FFN2 + b2 + residual(z) + LN2 -> out
  k_lngemm<<<256, 512, 0, stream>>>(hb, w2b, 2048, zf, b2, g2, be2, out, (bf16_t*)nullptr);
}

// Round 4
// 312.011 us; speedup vs baseline: 1.5579x; 1.5091x over previous
//
#include <hip/hip_runtime.h>
#include <math.h>
#include <stdint.h>

// GraphTransformerLayer on MI355X (gfx950).
// B=8, N=1024, D=512, H=8, Dh=64, F=2048.
// Round 4: all projection/FFN GEMMs -> tiled 128x64 MFMA kernel with
//          double-buffered global_load_lds staging (+16B-block XOR swizzle);
//          LayerNorms split into memory-bound k_resln passes.

using bf16_t = __bf16;
typedef __attribute__((__ext_vector_type__(8))) __bf16 bf16x8;
typedef __attribute__((__ext_vector_type__(4))) __bf16 bf16x4;
typedef __attribute__((__ext_vector_type__(4))) float  f32x4;

#define DEVI __device__ __forceinline__

DEVI f32x4 mfma16(bf16x8 a, bf16x8 b, f32x4 c) {
  return __builtin_amdgcn_mfma_f32_16x16x32_bf16(a, b, c, 0, 0, 0);
}

// async global->LDS, 16B per lane. dest = wave-uniform base (+ lane*16 by HW).
DEVI void gload_lds16(const void* g, void* l) {
  __builtin_amdgcn_global_load_lds(
      (const __attribute__((address_space(1))) uint32_t*)g,
      (__attribute__((address_space(3))) uint32_t*)l, 16, 0, 0);
}

__constant__ const float kScale = 0.125f;   // 1/sqrt(64)
#define NEGC  (-1.0e9f)
#define EPSC  (1e-5f)

// ---------------- f32 -> bf16 convert (vector4) ----------------
__global__ __launch_bounds__(256) void k_cvt(const float* __restrict__ in,
                                             bf16_t* __restrict__ out, int n4) {
  int i = blockIdx.x * 256 + threadIdx.x;
  if (i < n4) {
    float4 v = ((const float4*)in)[i];
    bf16x4 o = { (__bf16)v.x, (__bf16)v.y, (__bf16)v.z, (__bf16)v.w };
    ((bf16x4*)out)[i] = o;
  }
}

// ---------------- adjm = mask ? adj : NEG ; rowmax of masked adj ----------------
__global__ __launch_bounds__(256) void k_prep(const float* __restrict__ adj,
                                              const int* __restrict__ msk,
                                              float* __restrict__ adjm,
                                              float* __restrict__ rowmax) {
  int row  = blockIdx.x * 4 + (threadIdx.x >> 6);
  int lane = threadIdx.x & 63;
  float m = -INFINITY;
  for (int i = 0; i < 16; i++) {
    int c = lane + 64 * i;
    size_t idx = (size_t)row * 1024 + c;
    float a = adj[idx];
    bool valid = (msk[idx] != 0);
    adjm[idx] = valid ? a : NEGC;
    if (valid) m = fmaxf(m, a);
  }
  for (int off = 1; off < 64; off <<= 1) m = fmaxf(m, __shfl_xor(m, off));
  if (lane == 0) rowmax[row] = m;
}

// ---------------- tiled GEMM: C[8192 x N] = A[8192 x K] @ B[N x K]^T ----------------
// 128x64 tile, 4 waves (2x2), each wave 64x32 (4x2 fragments). BK=32.
// Double-buffered global_load_lds staging, 16B-block XOR swizzle (blk ^= row&3).
// EPI: 0 = bf16 store (with which-routing), 1 = bf16 bias+relu, 2 = f32 (+opt bias).
template<int EPI>
__global__ __launch_bounds__(256) void k_gemm(const bf16_t* __restrict__ A,
                                              const bf16_t* __restrict__ B,
                                              int K, int nbx,
                                              const float* __restrict__ bias,
                                              bf16_t* __restrict__ outb,
                                              float* __restrict__ outf,
                                              int out_ncols) {
  __shared__ bf16_t lA[2][4096];   // [128][32] bf16, 8KB per buf
  __shared__ bf16_t lB[2][2048];   // [64][32]  bf16, 4KB per buf
  int bid = blockIdx.x;
  int nb = bid % nbx, mb = bid / nbx;
  int tid = threadIdx.x, wid = tid >> 6, lane = tid & 63;
  int l16 = lane & 15, g = lane >> 4;
  int wr = wid >> 1, wc = wid & 1;
  int rowbase = mb * 128, c0 = nb * 64;

  // staging address precompute (source pre-swizzled; LDS dest linear)
  int dA0 = wid * 2048 + lane * 16;            // byte offset in A tile (instr 0)
  int rA0 = dA0 >> 6, rA1 = (dA0 + 1024) >> 6; // rows (64B per row)
  int bA  = (dA0 >> 4) & 3;                    // 16B block within row
  const bf16_t* Asrc0 = A + (size_t)(rowbase + rA0) * K + (bA ^ (rA0 & 3)) * 8;
  const bf16_t* Asrc1 = A + (size_t)(rowbase + rA1) * K + (bA ^ (rA1 & 3)) * 8;
  int dB = wid * 1024 + lane * 16;
  int rB = dB >> 6, bB = (dB >> 4) & 3;
  const bf16_t* Bsrc = B + (size_t)(c0 + rB) * K + (bB ^ (rB & 3)) * 8;

  f32x4 acc[4][2];
#pragma unroll
  for (int m = 0; m < 4; m++)
#pragma unroll
    for (int n = 0; n < 2; n++) acc[m][n] = (f32x4){0.f, 0.f, 0.f, 0.f};

  // prologue stage
  gload_lds16(Asrc0, &lA[0][wid * 1024]);
  gload_lds16(Asrc1, &lA[0][wid * 1024 + 512]);
  gload_lds16(Bsrc, &lB[0][wid * 512]);
  __syncthreads();

  for (int k0 = 0; k0 < K; k0 += 32) {
    int buf = (k0 >> 5) & 1;
    if (k0 + 32 < K) {
      gload_lds16(Asrc0 + k0 + 32, &lA[buf ^ 1][wid * 1024]);
      gload_lds16(Asrc1 + k0 + 32, &lA[buf ^ 1][wid * 1024 + 512]);
      gload_lds16(Bsrc + k0 + 32, &lB[buf ^ 1][wid * 512]);
    }
    const char* cA = (const char*)lA[buf];
    const char* cB = (const char*)lB[buf];
    bf16x8 af[4], bq[2];
#pragma unroll
    for (int m = 0; m < 4; m++) {
      int row = wr * 64 + m * 16 + l16;
      af[m] = *(const bf16x8*)(cA + row * 64 + ((g ^ (row & 3)) << 4));
    }
#pragma unroll
    for (int n = 0; n < 2; n++) {
      int row = wc * 32 + n * 16 + l16;
      bq[n] = *(const bf16x8*)(cB + row * 64 + ((g ^ (row & 3)) << 4));
    }
#pragma unroll
    for (int m = 0; m < 4; m++)
#pragma unroll
      for (int n = 0; n < 2; n++) acc[m][n] = mfma16(af[m], bq[n], acc[m][n]);
    __syncthreads();   // drains staged loads (vmcnt before barrier) + read fence
  }

  // epilogue
  int which = c0 / out_ncols;
  int cloc0 = c0 - which * out_ncols;
  size_t obase = (size_t)which * 8192 * out_ncols;
#pragma unroll
  for (int n = 0; n < 2; n++) {
    int col = cloc0 + wc * 32 + n * 16 + l16;
    float bv = (EPI >= 1 && bias) ? bias[col] : 0.f;
#pragma unroll
    for (int m = 0; m < 4; m++)
#pragma unroll
      for (int j = 0; j < 4; j++) {
        int row = rowbase + wr * 64 + m * 16 + g * 4 + j;
        float v = acc[m][n][j] + bv;
        size_t idx = obase + (size_t)row * out_ncols + col;
        if (EPI == 1) outb[idx] = (__bf16)fmaxf(v, 0.f);
        else if (EPI == 0) outb[idx] = (__bf16)v;
        else outf[idx] = v;
      }
  }
}

// ---------------- residual + LayerNorm (memory-bound): rows of 512 ----------------
// resid is f32 (residf) or bf16 (residb). outf / outb optional.
__global__ __launch_bounds__(256) void k_resln(const float* __restrict__ gin,
                                               const float* __restrict__ residf,
                                               const bf16_t* __restrict__ residb,
                                               const float* __restrict__ gam,
                                               const float* __restrict__ bet,
                                               float* __restrict__ outf,
                                               bf16_t* __restrict__ outb) {
  int row = blockIdx.x * 4 + (threadIdx.x >> 6);
  int lane = threadIdx.x & 63;
  const float* gp = gin + (size_t)row * 512;
  float4 a0 = ((const float4*)gp)[lane];
  float4 a1 = ((const float4*)gp)[lane + 64];
  if (residf) {
    const float* rp = residf + (size_t)row * 512;
    float4 r0 = ((const float4*)rp)[lane];
    float4 r1 = ((const float4*)rp)[lane + 64];
    a0.x += r0.x; a0.y += r0.y; a0.z += r0.z; a0.w += r0.w;
    a1.x += r1.x; a1.y += r1.y; a1.z += r1.z; a1.w += r1.w;
  } else {
    const bf16_t* rp = residb + (size_t)row * 512;
    bf16x4 r0 = ((const bf16x4*)rp)[lane];
    bf16x4 r1 = ((const bf16x4*)rp)[lane + 64];
    a0.x += (float)r0[0]; a0.y += (float)r0[1]; a0.z += (float)r0[2]; a0.w += (float)r0[3];
    a1.x += (float)r1[0]; a1.y += (float)r1[1]; a1.z += (float)r1[2]; a1.w += (float)r1[3];
  }
  float s = a0.x + a0.y + a0.z + a0.w + a1.x + a1.y + a1.z + a1.w;
  for (int off = 1; off < 64; off <<= 1) s += __shfl_xor(s, off);
  float mu = s * (1.f / 512.f);
  float sq = (a0.x - mu) * (a0.x - mu) + (a0.y - mu) * (a0.y - mu) +
             (a0.z - mu) * (a0.z - mu) + (a0.w - mu) * (a0.w - mu) +
             (a1.x - mu) * (a1.x - mu) + (a1.y - mu) * (a1.y - mu) +
             (a1.z - mu) * (a1.z - mu) + (a1.w - mu) * (a1.w - mu);
  for (int off = 1; off < 64; off <<= 1) sq += __shfl_xor(sq, off);
  float rs = rsqrtf(sq * (1.f / 512.f) + EPSC);

  float4 g0 = ((const float4*)gam)[lane], g1v = ((const float4*)gam)[lane + 64];
  float4 b0 = ((const float4*)bet)[lane], b1v = ((const float4*)bet)[lane + 64];
  float4 o0, o1;
  o0.x = (a0.x - mu) * rs * g0.x + b0.x;  o0.y = (a0.y - mu) * rs * g0.y + b0.y;
  o0.z = (a0.z - mu) * rs * g0.z + b0.z;  o0.w = (a0.w - mu) * rs * g0.w + b0.w;
  o1.x = (a1.x - mu) * rs * g1v.x + b1v.x; o1.y = (a1.y - mu) * rs * g1v.y + b1v.y;
  o1.z = (a1.z - mu) * rs * g1v.z + b1v.z; o1.w = (a1.w - mu) * rs * g1v.w + b1v.w;
  if (outf) {
    float* op = outf + (size_t)row * 512;
    ((float4*)op)[lane] = o0;
    ((float4*)op)[lane + 64] = o1;
  }
  if (outb) {
    bf16_t* op = outb + (size_t)row * 512;
    bf16x4 q0 = { (__bf16)o0.x, (__bf16)o0.y, (__bf16)o0.z, (__bf16)o0.w };
    bf16x4 q1 = { (__bf16)o1.x, (__bf16)o1.y, (__bf16)o1.z, (__bf16)o1.w };
    ((bf16x4*)op)[lane] = q0;
    ((bf16x4*)op)[lane + 64] = q1;
  }
}

// ---------------- v transpose: [B,N,H*64] -> vT [B,H,64,N] ----------------
__global__ __launch_bounds__(256) void k_vtrans(const bf16_t* __restrict__ v,
                                                bf16_t* __restrict__ vT) {
  int bid = blockIdx.x;
  int nt = bid & 15, h = (bid >> 4) & 7, b = bid >> 7;
  __shared__ bf16_t t[64 * 66];
  int tid = threadIdx.x, wid = tid >> 6, lane = tid & 63;
  for (int i = 0; i < 16; i++) {
    int n = wid * 16 + i;
    t[lane * 66 + n] = v[(size_t)(b * 1024 + nt * 64 + n) * 512 + h * 64 + lane];
  }
  __syncthreads();
  for (int i = 0; i < 16; i++) {
    int d = wid * 16 + i;
    vT[(size_t)((b * 8 + h) * 64 + d) * 1024 + nt * 64 + lane] = t[d * 66 + lane];
  }
}

// ---------------- max_n |k[b,h,n,:]| ----------------
__global__ __launch_bounds__(256) void k_knorm(const bf16_t* __restrict__ kk,
                                               float* __restrict__ kmax) {
  int bh = blockIdx.x;
  int b = bh >> 3, h = bh & 7;
  int tid = threadIdx.x;
  float mx = 0.f;
  for (int n = tid; n < 1024; n += 256) {
    const bf16_t* kp = kk + (size_t)(b * 1024 + n) * 512 + h * 64;
    float ss = 0.f;
#pragma unroll
    for (int vv = 0; vv < 8; vv++) {
      bf16x8 kv = *(const bf16x8*)(kp + vv * 8);
#pragma unroll
      for (int e = 0; e < 8; e++) { float f = (float)kv[e]; ss += f * f; }
    }
    mx = fmaxf(mx, ss);
  }
  for (int off = 1; off < 64; off <<= 1) mx = fmaxf(mx, __shfl_xor(mx, off));
  __shared__ float red[4];
  if ((tid & 63) == 0) red[tid >> 6] = mx;
  __syncthreads();
  if (tid == 0) kmax[bh] = sqrtf(fmaxf(fmaxf(red[0], red[1]), fmaxf(red[2], red[3])));
}

// ---------------- score upper bound C[b,h,n] = |q| * kmax / 8 + rowmax(adj) ----------------
__global__ __launch_bounds__(256) void k_cbound(const bf16_t* __restrict__ q,
                                                const float* __restrict__ kmax,
                                                const float* __restrict__ rowmax,
                                                float* __restrict__ Cb) {
  int t = blockIdx.x * 256 + threadIdx.x;  // (b*8+h)*1024 + n
  int b = t >> 13, h = (t >> 10) & 7, n = t & 1023;
  const bf16_t* qp = q + (size_t)(b * 1024 + n) * 512 + h * 64;
  float ss = 0.f;
#pragma unroll
  for (int vv = 0; vv < 8; vv++) {
    bf16x8 kv = *(const bf16x8*)(qp + vv * 8);
#pragma unroll
    for (int e = 0; e < 8; e++) { float f = (float)kv[e]; ss += f * f; }
  }
  float am = rowmax[n];
  Cb[t] = (am < -1e30f) ? 0.f : (sqrtf(ss) * kmax[b * 8 + h] * kScale + am);
}

// ---------------- attention partial: un-normalized ctx partial + partial l ----------------
// grid 2048: bid = split(1) | qt(4) | h(3) | b(3). Each block: 8 kt tiles of 64 k.
// K/vT tiles (8KB each) staged via global_load_lds, double-buffered, XOR-swizzled.
__global__ __launch_bounds__(256) void k_attn_ctx(const bf16_t* __restrict__ q,
                                                  const bf16_t* __restrict__ kk,
                                                  const bf16_t* __restrict__ vT,
                                                  const float* __restrict__ adjm,
                                                  const float* __restrict__ Cb,
                                                  float* __restrict__ lp,
                                                  bf16_t* __restrict__ ctxp0,
                                                  bf16_t* __restrict__ ctxp1) {
  __shared__ bf16_t ldsK[2][4096];      // 2 x 8KB : K tile  [64 k-rows][64 dh], swizzled
  __shared__ bf16_t ldsV[2][4096];      // 2 x 8KB : vT tile [64 d-rows][64 k],  swizzled
  __shared__ bf16_t pt[4][16 * 72];     // per-wave p tiles
  int bid = blockIdx.x;
  int split = bid & 1, qt = (bid >> 1) & 15, h = (bid >> 5) & 7, b = bid >> 8;
  int tid = threadIdx.x, wid = tid >> 6, lane = tid & 63;
  int l16 = lane & 15, g = lane >> 4;
  int qg0 = qt * 64 + wid * 16;
  bf16_t* ctxp = split ? ctxp1 : ctxp0;
  int kvbase = (b * 8 + h) * 64;

  int d0 = wid * 2048 + lane * 16;
  int row0 = d0 >> 7, row1 = (d0 + 1024) >> 7;
  int cb0 = ((d0 >> 4) & 7) ^ (row0 & 7);
  int cb1 = ((d0 >> 4) & 7) ^ (row1 & 7);
  const bf16_t* ksrc = kk + (size_t)(b * 1024) * 512 + h * 64;
  const bf16_t* vsrc = vT + (size_t)kvbase * 1024;

  auto stage = [&](int buf, int kc0) {
    gload_lds16(ksrc + (size_t)(kc0 + row0) * 512 + cb0 * 8, &ldsK[buf][wid * 1024]);
    gload_lds16(ksrc + (size_t)(kc0 + row1) * 512 + cb1 * 8, &ldsK[buf][wid * 1024 + 512]);
    gload_lds16(vsrc + (size_t)row0 * 1024 + kc0 + cb0 * 8, &ldsV[buf][wid * 1024]);
    gload_lds16(vsrc + (size_t)row1 * 1024 + kc0 + cb1 * 8, &ldsV[buf][wid * 1024 + 512]);
  };

  const bf16_t* qp = q + (size_t)(b * 1024 + qg0 + l16) * 512 + h * 64 + 8 * g;
  bf16x8 aq0 = *(const bf16x8*)qp;
  bf16x8 aq1 = *(const bf16x8*)(qp + 32);

  float Cj[4];
#pragma unroll
  for (int j = 0; j < 4; j++) Cj[j] = Cb[(b * 8 + h) * 1024 + qg0 + g * 4 + j];

  f32x4 cacc[4];
#pragma unroll
  for (int d = 0; d < 4; d++) cacc[d] = (f32x4){0.f, 0.f, 0.f, 0.f};
  float ls[4] = {0.f, 0.f, 0.f, 0.f};
  bf16_t* myp = pt[wid];  // wave-private
  int rph = l16 & 7;

  int ktS = split * 8, ktE = ktS + 8;
  stage(0, ktS * 64);
  __syncthreads();

  for (int kt = ktS; kt < ktE; ++kt) {
    int buf = (kt - ktS) & 1;
    int kc0 = kt * 64;
    int ktn = (kt + 1 < ktE) ? kt + 1 : kt;
    stage(buf ^ 1, ktn * 64);            // prefetch next tile (drains under compute)

    float am[4][4];                       // adjm for this tile, issued early
#pragma unroll
    for (int cg = 0; cg < 4; cg++)
#pragma unroll
      for (int j = 0; j < 4; j++)
        am[cg][j] = adjm[(size_t)(qg0 + g * 4 + j) * 1024 + kc0 + cg * 16 + l16];

    const char* curK = (const char*)ldsK[buf];
    const char* curV = (const char*)ldsV[buf];

#pragma unroll
    for (int cg = 0; cg < 4; cg++) {
      const char* krow = curK + ((cg * 16 + l16) << 7);
      bf16x8 k0 = *(const bf16x8*)(krow + ((g ^ rph) << 4));
      bf16x8 k1 = *(const bf16x8*)(krow + (((g + 4) ^ rph) << 4));
      f32x4 s = (f32x4){0.f, 0.f, 0.f, 0.f};
      s = mfma16(aq0, k0, s);
      s = mfma16(aq1, k1, s);
#pragma unroll
      for (int j = 0; j < 4; j++) {
        float sv = s[j] * kScale + am[cg][j];
        float p = __expf(sv - Cj[j]);
        ls[j] += p;
        myp[(g * 4 + j) * 72 + cg * 16 + l16] = (__bf16)p;
      }
    }
#pragma unroll
    for (int half = 0; half < 2; half++) {
      bf16x8 pa = *(const bf16x8*)(myp + l16 * 72 + half * 32 + 8 * g);
#pragma unroll
      for (int dg = 0; dg < 4; dg++) {
        const char* vrow = curV + ((dg * 16 + l16) << 7);
        bf16x8 vv = *(const bf16x8*)(vrow + (((g + half * 4) ^ rph) << 4));
        cacc[dg] = mfma16(pa, vv, cacc[dg]);
      }
    }
    __syncthreads();   // staged next tile complete; all waves done with buf
  }

#pragma unroll
  for (int j = 0; j < 4; j++)
    for (int off = 1; off < 16; off <<= 1) ls[j] += __shfl_xor(ls[j], off);

#pragma unroll
  for (int dg = 0; dg < 4; dg++)
#pragma unroll
    for (int j = 0; j < 4; j++) {
      int row = qg0 + g * 4 + j;
      ctxp[(size_t)(b * 1024 + row) * 512 + h * 64 + dg * 16 + l16] = (__bf16)cacc[dg][j];
    }
  if (l16 == 0) {
#pragma unroll
    for (int j = 0; j < 4; j++)
      lp[split * 65536 + (b * 8 + h) * 1024 + qg0 + g * 4 + j] = ls[j];
  }
}

// ---------------- combine partials -> ctx bf16, rcpl ----------------
__global__ __launch_bounds__(256) void k_attn_fin(const bf16_t* __restrict__ ctxp0,
                                                  const bf16_t* __restrict__ ctxp1,
                                                  const float* __restrict__ lp,
                                                  bf16_t* __restrict__ ctx,
                                                  float* __restrict__ rcpl) {
  int t = blockIdx.x * 256 + threadIdx.x;  // 1048576 groups of 4 elems
  int col4 = t & 127, row = t >> 7;
  int b = row >> 10, qq = row & 1023, h = col4 >> 4;
  int li = (b * 8 + h) * 1024 + qq;
  float l = lp[li] + lp[65536 + li];
  float rc = (l > 0.f) ? (1.f / l) : 0.f;
  bf16x4 p0 = ((const bf16x4*)ctxp0)[t];
  bf16x4 p1 = ((const bf16x4*)ctxp1)[t];
  bf16x4 o;
#pragma unroll
  for (int i = 0; i < 4; i++) o[i] = (__bf16)(((float)p0[i] + (float)p1[i]) * rc);
  ((bf16x4*)ctx)[t] = o;
  if ((col4 & 15) == 0) rcpl[li] = rc;
}

// ---------------- attention mean over heads -> d_out[4.19M .. ] ----------------
// grid 2048: bid = kq(2) | qt(6) | b(3). Block: 16 q rows x 256 k cols, loop 8 heads.
__global__ __launch_bounds__(256) void k_attn_mean(const bf16_t* __restrict__ q,
                                                   const bf16_t* __restrict__ kk,
                                                   const float* __restrict__ adjm,
                                                   const float* __restrict__ Cb,
                                                   const float* __restrict__ rcpl,
                                                   float* __restrict__ mout) {
  int bid = blockIdx.x;
  int kq = bid & 3, qt = (bid >> 2) & 63, b = bid >> 8;
  int tid = threadIdx.x, wid = tid >> 6, lane = tid & 63;
  int l16 = lane & 15, g = lane >> 4;
  int qg0 = qt * 16;
  int kc0 = kq * 256 + wid * 64;

  float av[4][4];
#pragma unroll
  for (int cg = 0; cg < 4; cg++)
#pragma unroll
    for (int j = 0; j < 4; j++)
      av[cg][j] = adjm[(size_t)(qg0 + g * 4 + j) * 1024 + kc0 + cg * 16 + l16];

  f32x4 macc[4];
#pragma unroll
  for (int cg = 0; cg < 4; cg++) macc[cg] = (f32x4){0.f, 0.f, 0.f, 0.f};

  for (int h = 0; h < 8; h++) {
    const bf16_t* qp = q + (size_t)(b * 1024 + qg0 + l16) * 512 + h * 64 + 8 * g;
    bf16x8 aq0 = *(const bf16x8*)qp;
    bf16x8 aq1 = *(const bf16x8*)(qp + 32);
    float Cj[4], Rj[4];
#pragma unroll
    for (int j = 0; j < 4; j++) {
      int sidx = (b * 8 + h) * 1024 + qg0 + g * 4 + j;
      Cj[j] = Cb[sidx];
      Rj[j] = rcpl[sidx];
    }
#pragma unroll
    for (int cg = 0; cg < 4; cg++) {
      const bf16_t* kp = kk + (size_t)(b * 1024 + kc0 + cg * 16 + l16) * 512 + h * 64 + 8 * g;
      f32x4 s = (f32x4){0.f, 0.f, 0.f, 0.f};
      s = mfma16(aq0, *(const bf16x8*)kp, s);
      s = mfma16(aq1, *(const bf16x8*)(kp + 32), s);
      f32x4 m = macc[cg];
#pragma unroll
      for (int j = 0; j < 4; j++) {
        float sv = s[j] * kScale + av[cg][j];
        m[j] += __expf(sv - Cj[j]) * Rj[j];
      }
      macc[cg] = m;
    }
  }
#pragma unroll
  for (int cg = 0; cg < 4; cg++)
#pragma unroll
    for (int j = 0; j < 4; j++)
      mout[(size_t)(b * 1024 + qg0 + g * 4 + j) * 1024 + kc0 + cg * 16 + l16] =
          macc[cg][j] * 0.125f;
}

extern "C" void kernel_launch(void* const* d_in, const int* in_sizes, int n_in,
                              void* d_out, int out_size, void* d_ws, size_t ws_size,
                              hipStream_t stream) {
  (void)in_sizes; (void)n_in; (void)out_size; (void)ws_size;
  const float* x   = (const float*)d_in[0];
  const float* adj = (const float*)d_in[1];
  const int*   msk = (const int*)d_in[2];
  const float* Wq  = (const float*)d_in[3];
  const float* Wk  = (const float*)d_in[4];
  const float* Wv  = (const float*)d_in[5];
  const float* Wo  = (const float*)d_in[6];
  const float* W1  = (const float*)d_in[7];
  const float* b1  = (const float*)d_in[8];
  const float* W2  = (const float*)d_in[9];
  const float* b2  = (const float*)d_in[10];
  const float* g1  = (const float*)d_in[11];
  const float* be1 = (const float*)d_in[12];
  const float* g2  = (const float*)d_in[13];
  const float* be2 = (const float*)d_in[14];

  float* out  = (float*)d_out;
  float* mout = out + (size_t)8 * 1024 * 512;

  char* ws = (char*)d_ws;
  const size_t MB = 1024 * 1024;
  // weights (contiguous wq|wk|wv for the fused qkv GEMM)
  bf16_t* wqb = (bf16_t*)(ws);                 // 0.0-0.5 MB
  bf16_t* wkb = (bf16_t*)(ws + 512 * 1024);    // 0.5-1.0
  bf16_t* wvb = (bf16_t*)(ws + 1 * MB);        // 1.0-1.5
  bf16_t* wob = (bf16_t*)(ws + 3 * MB / 2);    // 1.5-2.0
  bf16_t* w1b = (bf16_t*)(ws + 2 * MB);        // 2-4
  bf16_t* w2b = (bf16_t*)(ws + 4 * MB);        // 4-6
  float*  Cb   = (float*)(ws + 6 * MB);              // 256 KB
  float*  rcpl = (float*)(ws + 6 * MB + 256 * 1024); // 256 KB
  float*  amax = (float*)(ws + 6 * MB + 512 * 1024); // 4 KB
  float*  kmax = (float*)(ws + 6 * MB + 768 * 1024); // 256 B
  float*  lp   = (float*)(ws + 7 * MB);              // 512 KB
  // big buffers with lifetime reuse:
  bf16_t* xb   = (bf16_t*)(ws + 8 * MB);   // 8-16: x bf16 (dead after qkv); then ctx; then zb
  bf16_t* ctx  = xb;                       //   (attn_fin -> wo-gemm)
  bf16_t* zb   = xb;                       //   (resln1 -> ffn1 + resln2 resid)
  bf16_t* qb   = (bf16_t*)(ws + 16 * MB);  // 16-24 (dead after attn_mean)
  bf16_t* kb   = (bf16_t*)(ws + 24 * MB);  // 24-32 (dead after attn_mean)
  bf16_t* vb   = (bf16_t*)(ws + 32 * MB);  // 32-40 (dead after vtrans)
  bf16_t* ctxp1 = vb;                      //   partial ctx split 1
  bf16_t* vT   = (bf16_t*)(ws + 40 * MB);  // 40-48 (dead after attn_ctx)
  bf16_t* ctxp0 = (bf16_t*)(ws + 48 * MB); // 48-56 (dead after attn_fin)
  float*  gout1 = (float*)(ws + 16 * MB);  // 16-32 f32 (wo-gemm -> resln1)
  bf16_t* hb    = (bf16_t*)(ws + 16 * MB); // 16-48 bf16 (ffn1 -> ffn2)
  float*  gout2 = (float*)(ws + 48 * MB);  // 48-64 f32 (ffn2 -> resln2)
  float*  adjm  = (float*)(ws + 72 * MB);  // 72-76

  // converts
  k_cvt<<<4096, 256, 0, stream>>>(x,  xb,  1048576);
  k_cvt<<<256,  256, 0, stream>>>(Wq, wqb, 65536);
  k_cvt<<<256,  256, 0, stream>>>(Wk, wkb, 65536);
  k_cvt<<<256,  256, 0, stream>>>(Wv, wvb, 65536);
  k_cvt<<<256,  256, 0, stream>>>(Wo, wob, 65536);
  k_cvt<<<1024, 256, 0, stream>>>(W1, w1b, 262144);
  k_cvt<<<1024, 256, 0, stream>>>(W2, w2b, 262144);

  k_prep<<<256, 256, 0, stream>>>(adj, msk, adjm, amax);

  // QKV: one GEMM, N=1536 (wq|wk|wv contiguous), outputs routed to qb|kb|vb
  k_gemm<0><<<64 * 24, 256, 0, stream>>>(xb, wqb, 512, 24, nullptr, qb, nullptr, 512);
  k_vtrans<<<1024, 256, 0, stream>>>(vb, vT);
  k_knorm<<<64, 256, 0, stream>>>(kb, kmax);
  k_cbound<<<256, 256, 0, stream>>>(qb, kmax, amax, Cb);

  // attention: partials (k-split x2), combine, mean
  k_attn_ctx<<<2048, 256, 0, stream>>>(qb, kb, vT, adjm, Cb, lp, ctxp0, ctxp1);
  k_attn_fin<<<4096, 256, 0, stream>>>(ctxp0, ctxp1, lp, ctx, rcpl);
  k_attn_mean<<<2048, 256, 0, stream>>>(qb, kb, adjm, Cb, rcpl, mout);

  // Wo proj -> gout1 ; residual(x f32) + LN1 -> zb (bf16)
  k_gemm<2><<<64 * 8, 256, 0, stream>>>(ctx, wob, 512, 8, nullptr, nullptr, gout1, 512);
  k_resln<<<2048, 256, 0, stream>>>(gout1, x, nullptr, g1, be1, nullptr, zb);
  // FFN1: relu(zb @ W1^T + b1) -> hb
  k_gemm<1><<<64 * 32, 256, 0, stream>>>(zb, w1b, 512, 32, b1, hb, nullptr, 2048);
  // FFN2 -> gout2 ; residual(zb bf16) + LN2 -> out
  k_gemm<2><<<64 * 8, 256, 0, stream>>>(hb, w2b, 2048, 8, b2, nullptr, gout2, 512);
  k_resln<<<2048, 256, 0, stream>>>(gout2, nullptr, zb, g2, be2, out, nullptr);
}

// Round 5
// 279.786 us; speedup vs baseline: 1.7373x; 1.1152x over previous
//
#include <hip/hip_runtime.h>
#include <math.h>
#include <stdint.h>

// GraphTransformerLayer on MI355X (gfx950).
// B=8, N=1024, D=512, H=8, Dh=64, F=2048.
// Round 5: attn_mean rebuilt on the dbuf global_load_lds staging template
//          (8KB K tiles, XOR swizzle, 1 barrier/stage); 1/l folded into
//          crl = C + ln(l); q pre-scaled by 0.125 at QKV epilogue.

using bf16_t = __bf16;
typedef __attribute__((__ext_vector_type__(8))) __bf16 bf16x8;
typedef __attribute__((__ext_vector_type__(4))) __bf16 bf16x4;
typedef __attribute__((__ext_vector_type__(4))) float  f32x4;

#define DEVI __device__ __forceinline__

DEVI f32x4 mfma16(bf16x8 a, bf16x8 b, f32x4 c) {
  return __builtin_amdgcn_mfma_f32_16x16x32_bf16(a, b, c, 0, 0, 0);
}

// async global->LDS, 16B per lane. dest = wave-uniform base (+ lane*16 by HW).
DEVI void gload_lds16(const void* g, void* l) {
  __builtin_amdgcn_global_load_lds(
      (const __attribute__((address_space(1))) uint32_t*)g,
      (__attribute__((address_space(3))) uint32_t*)l, 16, 0, 0);
}

#define NEGC  (-1.0e9f)
#define EPSC  (1e-5f)

// ---------------- f32 -> bf16 convert (vector4) ----------------
__global__ __launch_bounds__(256) void k_cvt(const float* __restrict__ in,
                                             bf16_t* __restrict__ out, int n4) {
  int i = blockIdx.x * 256 + threadIdx.x;
  if (i < n4) {
    float4 v = ((const float4*)in)[i];
    bf16x4 o = { (__bf16)v.x, (__bf16)v.y, (__bf16)v.z, (__bf16)v.w };
    ((bf16x4*)out)[i] = o;
  }
}

// ---------------- adjm = mask ? adj : NEG ; rowmax of masked adj ----------------
__global__ __launch_bounds__(256) void k_prep(const float* __restrict__ adj,
                                              const int* __restrict__ msk,
                                              float* __restrict__ adjm,
                                              float* __restrict__ rowmax) {
  int row  = blockIdx.x * 4 + (threadIdx.x >> 6);
  int lane = threadIdx.x & 63;
  float m = -INFINITY;
  for (int i = 0; i < 16; i++) {
    int c = lane + 64 * i;
    size_t idx = (size_t)row * 1024 + c;
    float a = adj[idx];
    bool valid = (msk[idx] != 0);
    adjm[idx] = valid ? a : NEGC;
    if (valid) m = fmaxf(m, a);
  }
  for (int off = 1; off < 64; off <<= 1) m = fmaxf(m, __shfl_xor(m, off));
  if (lane == 0) rowmax[row] = m;
}

// ---------------- tiled GEMM: C[8192 x N] = A[8192 x K] @ B[N x K]^T ----------------
// 128x64 tile, 4 waves (2x2), each wave 64x32 (4x2 fragments). BK=32.
// Double-buffered global_load_lds staging, 16B-block XOR swizzle (blk ^= row&3).
// EPI: 0 = bf16 store with which-routing (which==0 scaled by 0.125 for q),
//      1 = bf16 bias+relu, 2 = f32 (+opt bias).
template<int EPI>
__global__ __launch_bounds__(256) void k_gemm(const bf16_t* __restrict__ A,
                                              const bf16_t* __restrict__ B,
                                              int K, int nbx,
                                              const float* __restrict__ bias,
                                              bf16_t* __restrict__ outb,
                                              float* __restrict__ outf,
                                              int out_ncols) {
  __shared__ bf16_t lA[2][4096];   // [128][32] bf16, 8KB per buf
  __shared__ bf16_t lB[2][2048];   // [64][32]  bf16, 4KB per buf
  int bid = blockIdx.x;
  int nb = bid % nbx, mb = bid / nbx;
  int tid = threadIdx.x, wid = tid >> 6, lane = tid & 63;
  int l16 = lane & 15, g = lane >> 4;
  int wr = wid >> 1, wc = wid & 1;
  int rowbase = mb * 128, c0 = nb * 64;

  int dA0 = wid * 2048 + lane * 16;
  int rA0 = dA0 >> 6, rA1 = (dA0 + 1024) >> 6;
  int bA  = (dA0 >> 4) & 3;
  const bf16_t* Asrc0 = A + (size_t)(rowbase + rA0) * K + (bA ^ (rA0 & 3)) * 8;
  const bf16_t* Asrc1 = A + (size_t)(rowbase + rA1) * K + (bA ^ (rA1 & 3)) * 8;
  int dB = wid * 1024 + lane * 16;
  int rB = dB >> 6, bB = (dB >> 4) & 3;
  const bf16_t* Bsrc = B + (size_t)(c0 + rB) * K + (bB ^ (rB & 3)) * 8;

  f32x4 acc[4][2];
#pragma unroll
  for (int m = 0; m < 4; m++)
#pragma unroll
    for (int n = 0; n < 2; n++) acc[m][n] = (f32x4){0.f, 0.f, 0.f, 0.f};

  gload_lds16(Asrc0, &lA[0][wid * 1024]);
  gload_lds16(Asrc1, &lA[0][wid * 1024 + 512]);
  gload_lds16(Bsrc, &lB[0][wid * 512]);
  __syncthreads();

  for (int k0 = 0; k0 < K; k0 += 32) {
    int buf = (k0 >> 5) & 1;
    if (k0 + 32 < K) {
      gload_lds16(Asrc0 + k0 + 32, &lA[buf ^ 1][wid * 1024]);
      gload_lds16(Asrc1 + k0 + 32, &lA[buf ^ 1][wid * 1024 + 512]);
      gload_lds16(Bsrc + k0 + 32, &lB[buf ^ 1][wid * 512]);
    }
    const char* cA = (const char*)lA[buf];
    const char* cB = (const char*)lB[buf];
    bf16x8 af[4], bq[2];
#pragma unroll
    for (int m = 0; m < 4; m++) {
      int row = wr * 64 + m * 16 + l16;
      af[m] = *(const bf16x8*)(cA + row * 64 + ((g ^ (row & 3)) << 4));
    }
#pragma unroll
    for (int n = 0; n < 2; n++) {
      int row = wc * 32 + n * 16 + l16;
      bq[n] = *(const bf16x8*)(cB + row * 64 + ((g ^ (row & 3)) << 4));
    }
#pragma unroll
    for (int m = 0; m < 4; m++)
#pragma unroll
      for (int n = 0; n < 2; n++) acc[m][n] = mfma16(af[m], bq[n], acc[m][n]);
    __syncthreads();
  }

  int which = c0 / out_ncols;
  int cloc0 = c0 - which * out_ncols;
  size_t obase = (size_t)which * 8192 * out_ncols;
  float osc = (EPI == 0 && which == 0) ? 0.125f : 1.0f;  // q pre-scale
#pragma unroll
  for (int n = 0; n < 2; n++) {
    int col = cloc0 + wc * 32 + n * 16 + l16;
    float bv = (EPI >= 1 && bias) ? bias[col] : 0.f;
#pragma unroll
    for (int m = 0; m < 4; m++)
#pragma unroll
      for (int j = 0; j < 4; j++) {
        int row = rowbase + wr * 64 + m * 16 + g * 4 + j;
        float v = acc[m][n][j] + bv;
        size_t idx = obase + (size_t)row * out_ncols + col;
        if (EPI == 1) outb[idx] = (__bf16)fmaxf(v, 0.f);
        else if (EPI == 0) outb[idx] = (__bf16)(v * osc);
        else outf[idx] = v;
      }
  }
}

// ---------------- residual + LayerNorm (memory-bound): rows of 512 ----------------
__global__ __launch_bounds__(256) void k_resln(const float* __restrict__ gin,
                                               const float* __restrict__ residf,
                                               const bf16_t* __restrict__ residb,
                                               const float* __restrict__ gam,
                                               const float* __restrict__ bet,
                                               float* __restrict__ outf,
                                               bf16_t* __restrict__ outb) {
  int row = blockIdx.x * 4 + (threadIdx.x >> 6);
  int lane = threadIdx.x & 63;
  const float* gp = gin + (size_t)row * 512;
  float4 a0 = ((const float4*)gp)[lane];
  float4 a1 = ((const float4*)gp)[lane + 64];
  if (residf) {
    const float* rp = residf + (size_t)row * 512;
    float4 r0 = ((const float4*)rp)[lane];
    float4 r1 = ((const float4*)rp)[lane + 64];
    a0.x += r0.x; a0.y += r0.y; a0.z += r0.z; a0.w += r0.w;
    a1.x += r1.x; a1.y += r1.y; a1.z += r1.z; a1.w += r1.w;
  } else {
    const bf16_t* rp = residb + (size_t)row * 512;
    bf16x4 r0 = ((const bf16x4*)rp)[lane];
    bf16x4 r1 = ((const bf16x4*)rp)[lane + 64];
    a0.x += (float)r0[0]; a0.y += (float)r0[1]; a0.z += (float)r0[2]; a0.w += (float)r0[3];
    a1.x += (float)r1[0]; a1.y += (float)r1[1]; a1.z += (float)r1[2]; a1.w += (float)r1[3];
  }
  float s = a0.x + a0.y + a0.z + a0.w + a1.x + a1.y + a1.z + a1.w;
  for (int off = 1; off < 64; off <<= 1) s += __shfl_xor(s, off);
  float mu = s * (1.f / 512.f);
  float sq = (a0.x - mu) * (a0.x - mu) + (a0.y - mu) * (a0.y - mu) +
             (a0.z - mu) * (a0.z - mu) + (a0.w - mu) * (a0.w - mu) +
             (a1.x - mu) * (a1.x - mu) + (a1.y - mu) * (a1.y - mu) +
             (a1.z - mu) * (a1.z - mu) + (a1.w - mu) * (a1.w - mu);
  for (int off = 1; off < 64; off <<= 1) sq += __shfl_xor(sq, off);
  float rs = rsqrtf(sq * (1.f / 512.f) + EPSC);

  float4 g0 = ((const float4*)gam)[lane], g1v = ((const float4*)gam)[lane + 64];
  float4 b0 = ((const float4*)bet)[lane], b1v = ((const float4*)bet)[lane + 64];
  float4 o0, o1;
  o0.x = (a0.x - mu) * rs * g0.x + b0.x;  o0.y = (a0.y - mu) * rs * g0.y + b0.y;
  o0.z = (a0.z - mu) * rs * g0.z + b0.z;  o0.w = (a0.w - mu) * rs * g0.w + b0.w;
  o1.x = (a1.x - mu) * rs * g1v.x + b1v.x; o1.y = (a1.y - mu) * rs * g1v.y + b1v.y;
  o1.z = (a1.z - mu) * rs * g1v.z + b1v.z; o1.w = (a1.w - mu) * rs * g1v.w + b1v.w;
  if (outf) {
    float* op = outf + (size_t)row * 512;
    ((float4*)op)[lane] = o0;
    ((float4*)op)[lane + 64] = o1;
  }
  if (outb) {
    bf16_t* op = outb + (size_t)row * 512;
    bf16x4 q0 = { (__bf16)o0.x, (__bf16)o0.y, (__bf16)o0.z, (__bf16)o0.w };
    bf16x4 q1 = { (__bf16)o1.x, (__bf16)o1.y, (__bf16)o1.z, (__bf16)o1.w };
    ((bf16x4*)op)[lane] = q0;
    ((bf16x4*)op)[lane + 64] = q1;
  }
}

// ---------------- v transpose: [B,N,H*64] -> vT [B,H,64,N] ----------------
__global__ __launch_bounds__(256) void k_vtrans(const bf16_t* __restrict__ v,
                                                bf16_t* __restrict__ vT) {
  int bid = blockIdx.x;
  int nt = bid & 15, h = (bid >> 4) & 7, b = bid >> 7;
  __shared__ bf16_t t[64 * 66];
  int tid = threadIdx.x, wid = tid >> 6, lane = tid & 63;
  for (int i = 0; i < 16; i++) {
    int n = wid * 16 + i;
    t[lane * 66 + n] = v[(size_t)(b * 1024 + nt * 64 + n) * 512 + h * 64 + lane];
  }
  __syncthreads();
  for (int i = 0; i < 16; i++) {
    int d = wid * 16 + i;
    vT[(size_t)((b * 8 + h) * 64 + d) * 1024 + nt * 64 + lane] = t[d * 66 + lane];
  }
}

// ---------------- max_n |k[b,h,n,:]| ----------------
__global__ __launch_bounds__(256) void k_knorm(const bf16_t* __restrict__ kk,
                                               float* __restrict__ kmax) {
  int bh = blockIdx.x;
  int b = bh >> 3, h = bh & 7;
  int tid = threadIdx.x;
  float mx = 0.f;
  for (int n = tid; n < 1024; n += 256) {
    const bf16_t* kp = kk + (size_t)(b * 1024 + n) * 512 + h * 64;
    float ss = 0.f;
#pragma unroll
    for (int vv = 0; vv < 8; vv++) {
      bf16x8 kv = *(const bf16x8*)(kp + vv * 8);
#pragma unroll
      for (int e = 0; e < 8; e++) { float f = (float)kv[e]; ss += f * f; }
    }
    mx = fmaxf(mx, ss);
  }
  for (int off = 1; off < 64; off <<= 1) mx = fmaxf(mx, __shfl_xor(mx, off));
  __shared__ float red[4];
  if ((tid & 63) == 0) red[tid >> 6] = mx;
  __syncthreads();
  if (tid == 0) kmax[bh] = sqrtf(fmaxf(fmaxf(red[0], red[1]), fmaxf(red[2], red[3])));
}

// ---------------- score upper bound C[b,h,n] = |q'| * kmax + rowmax(adj) ----------------
// (q is pre-scaled by 0.125, so no kScale here)
__global__ __launch_bounds__(256) void k_cbound(const bf16_t* __restrict__ q,
                                                const float* __restrict__ kmax,
                                                const float* __restrict__ rowmax,
                                                float* __restrict__ Cb) {
  int t = blockIdx.x * 256 + threadIdx.x;  // (b*8+h)*1024 + n
  int b = t >> 13, h = (t >> 10) & 7, n = t & 1023;
  const bf16_t* qp = q + (size_t)(b * 1024 + n) * 512 + h * 64;
  float ss = 0.f;
#pragma unroll
  for (int vv = 0; vv < 8; vv++) {
    bf16x8 kv = *(const bf16x8*)(qp + vv * 8);
#pragma unroll
    for (int e = 0; e < 8; e++) { float f = (float)kv[e]; ss += f * f; }
  }
  float am = rowmax[n];
  Cb[t] = (am < -1e30f) ? 0.f : (sqrtf(ss) * kmax[b * 8 + h] + am);
}

// ---------------- attention partial: un-normalized ctx partial + partial l ----------------
__global__ __launch_bounds__(256) void k_attn_ctx(const bf16_t* __restrict__ q,
                                                  const bf16_t* __restrict__ kk,
                                                  const bf16_t* __restrict__ vT,
                                                  const float* __restrict__ adjm,
                                                  const float* __restrict__ Cb,
                                                  float* __restrict__ lp,
                                                  bf16_t* __restrict__ ctxp0,
                                                  bf16_t* __restrict__ ctxp1) {
  __shared__ bf16_t ldsK[2][4096];
  __shared__ bf16_t ldsV[2][4096];
  __shared__ bf16_t pt[4][16 * 72];
  int bid = blockIdx.x;
  int split = bid & 1, qt = (bid >> 1) & 15, h = (bid >> 5) & 7, b = bid >> 8;
  int tid = threadIdx.x, wid = tid >> 6, lane = tid & 63;
  int l16 = lane & 15, g = lane >> 4;
  int qg0 = qt * 64 + wid * 16;
  bf16_t* ctxp = split ? ctxp1 : ctxp0;
  int kvbase = (b * 8 + h) * 64;

  int d0 = wid * 2048 + lane * 16;
  int row0 = d0 >> 7, row1 = (d0 + 1024) >> 7;
  int cb0 = ((d0 >> 4) & 7) ^ (row0 & 7);
  int cb1 = ((d0 >> 4) & 7) ^ (row1 & 7);
  const bf16_t* ksrc = kk + (size_t)(b * 1024) * 512 + h * 64;
  const bf16_t* vsrc = vT + (size_t)kvbase * 1024;

  auto stage = [&](int buf, int kc0) {
    gload_lds16(ksrc + (size_t)(kc0 + row0) * 512 + cb0 * 8, &ldsK[buf][wid * 1024]);
    gload_lds16(ksrc + (size_t)(kc0 + row1) * 512 + cb1 * 8, &ldsK[buf][wid * 1024 + 512]);
    gload_lds16(vsrc + (size_t)row0 * 1024 + kc0 + cb0 * 8, &ldsV[buf][wid * 1024]);
    gload_lds16(vsrc + (size_t)row1 * 1024 + kc0 + cb1 * 8, &ldsV[buf][wid * 1024 + 512]);
  };

  const bf16_t* qp = q + (size_t)(b * 1024 + qg0 + l16) * 512 + h * 64 + 8 * g;
  bf16x8 aq0 = *(const bf16x8*)qp;
  bf16x8 aq1 = *(const bf16x8*)(qp + 32);

  float Cj[4];
#pragma unroll
  for (int j = 0; j < 4; j++) Cj[j] = Cb[(b * 8 + h) * 1024 + qg0 + g * 4 + j];

  f32x4 cacc[4];
#pragma unroll
  for (int d = 0; d < 4; d++) cacc[d] = (f32x4){0.f, 0.f, 0.f, 0.f};
  float ls[4] = {0.f, 0.f, 0.f, 0.f};
  bf16_t* myp = pt[wid];
  int rph = l16 & 7;

  int ktS = split * 8, ktE = ktS + 8;
  stage(0, ktS * 64);
  __syncthreads();

  for (int kt = ktS; kt < ktE; ++kt) {
    int buf = (kt - ktS) & 1;
    int kc0 = kt * 64;
    int ktn = (kt + 1 < ktE) ? kt + 1 : kt;
    stage(buf ^ 1, ktn * 64);

    float am[4][4];
#pragma unroll
    for (int cg = 0; cg < 4; cg++)
#pragma unroll
      for (int j = 0; j < 4; j++)
        am[cg][j] = adjm[(size_t)(qg0 + g * 4 + j) * 1024 + kc0 + cg * 16 + l16];

    const char* curK = (const char*)ldsK[buf];
    const char* curV = (const char*)ldsV[buf];

#pragma unroll
    for (int cg = 0; cg < 4; cg++) {
      const char* krow = curK + ((cg * 16 + l16) << 7);
      bf16x8 k0 = *(const bf16x8*)(krow + ((g ^ rph) << 4));
      bf16x8 k1 = *(const bf16x8*)(krow + (((g + 4) ^ rph) << 4));
      f32x4 s = (f32x4){0.f, 0.f, 0.f, 0.f};
      s = mfma16(aq0, k0, s);
      s = mfma16(aq1, k1, s);
#pragma unroll
      for (int j = 0; j < 4; j++) {
        float sv = s[j] + am[cg][j];
        float p = __expf(sv - Cj[j]);
        ls[j] += p;
        myp[(g * 4 + j) * 72 + cg * 16 + l16] = (__bf16)p;
      }
    }
#pragma unroll
    for (int half = 0; half < 2; half++) {
      bf16x8 pa = *(const bf16x8*)(myp + l16 * 72 + half * 32 + 8 * g);
#pragma unroll
      for (int dg = 0; dg < 4; dg++) {
        const char* vrow = curV + ((dg * 16 + l16) << 7);
        bf16x8 vv = *(const bf16x8*)(vrow + (((g + half * 4) ^ rph) << 4));
        cacc[dg] = mfma16(pa, vv, cacc[dg]);
      }
    }
    __syncthreads();
  }

#pragma unroll
  for (int j = 0; j < 4; j++)
    for (int off = 1; off < 16; off <<= 1) ls[j] += __shfl_xor(ls[j], off);

#pragma unroll
  for (int dg = 0; dg < 4; dg++)
#pragma unroll
    for (int j = 0; j < 4; j++) {
      int row = qg0 + g * 4 + j;
      ctxp[(size_t)(b * 1024 + row) * 512 + h * 64 + dg * 16 + l16] = (__bf16)cacc[dg][j];
    }
  if (l16 == 0) {
#pragma unroll
    for (int j = 0; j < 4; j++)
      lp[split * 65536 + (b * 8 + h) * 1024 + qg0 + g * 4 + j] = ls[j];
  }
}

// ---------------- combine partials -> ctx bf16, crl = C + ln(l) ----------------
__global__ __launch_bounds__(256) void k_attn_fin(const bf16_t* __restrict__ ctxp0,
                                                  const bf16_t* __restrict__ ctxp1,
                                                  const float* __restrict__ lp,
                                                  const float* __restrict__ Cb,
                                                  bf16_t* __restrict__ ctx,
                                                  float* __restrict__ crl) {
  int t = blockIdx.x * 256 + threadIdx.x;  // 1048576 groups of 4 elems
  int col4 = t & 127, row = t >> 7;
  int b = row >> 10, qq = row & 1023, h = col4 >> 4;
  int li = (b * 8 + h) * 1024 + qq;
  float l = lp[li] + lp[65536 + li];
  float rc = (l > 0.f) ? (1.f / l) : 0.f;
  bf16x4 p0 = ((const bf16x4*)ctxp0)[t];
  bf16x4 p1 = ((const bf16x4*)ctxp1)[t];
  bf16x4 o;
#pragma unroll
  for (int i = 0; i < 4; i++) o[i] = (__bf16)(((float)p0[i] + (float)p1[i]) * rc);
  ((bf16x4*)ctx)[t] = o;
  if ((col4 & 15) == 0)
    crl[li] = (l > 0.f) ? (Cb[li] + __logf(l)) : 1.0e30f;
}

// ---------------- attention mean over heads -> mout ----------------
// grid 1024: bid = kq(3) | qt(4) | b(3). Block: 64 q (4 waves x 16) x 128 k,
// loop h(8) x kt(2); 8KB K tiles dbuf-staged via global_load_lds (XOR swizzle).
__global__ __launch_bounds__(256) void k_attn_mean(const bf16_t* __restrict__ q,
                                                   const bf16_t* __restrict__ kk,
                                                   const float* __restrict__ adjm,
                                                   const float* __restrict__ crl,
                                                   float* __restrict__ mout) {
  __shared__ bf16_t ldsK[2][4096];
  int bid = blockIdx.x;
  int kq = bid & 7, qt = (bid >> 3) & 15, b = bid >> 7;
  int tid = threadIdx.x, wid = tid >> 6, lane = tid & 63;
  int l16 = lane & 15, g = lane >> 4;
  int qg0 = qt * 64 + wid * 16;
  int kbase = kq * 128;
  int rph = l16 & 7;

  int d0 = wid * 2048 + lane * 16;
  int row0 = d0 >> 7, row1 = (d0 + 1024) >> 7;
  int cb0 = ((d0 >> 4) & 7) ^ (row0 & 7);
  int cb1 = ((d0 >> 4) & 7) ^ (row1 & 7);
  const bf16_t* ksrc = kk + (size_t)(b * 1024) * 512;

  auto stage = [&](int buf, int kt, int h) {
    gload_lds16(ksrc + (size_t)(kbase + kt * 64 + row0) * 512 + h * 64 + cb0 * 8,
                (char*)&ldsK[0][0] + buf * 8192 + wid * 2048);
    gload_lds16(ksrc + (size_t)(kbase + kt * 64 + row1) * 512 + h * 64 + cb1 * 8,
                (char*)&ldsK[0][0] + buf * 8192 + wid * 2048 + 1024);
  };

  // adjm preload for the whole 64q x 128k block slice of this wave
  float av[8][4];
#pragma unroll
  for (int c8 = 0; c8 < 8; c8++)
#pragma unroll
    for (int j = 0; j < 4; j++)
      av[c8][j] = adjm[(size_t)(qg0 + g * 4 + j) * 1024 + kbase + c8 * 16 + l16];

  f32x4 macc[8];
#pragma unroll
  for (int c8 = 0; c8 < 8; c8++) macc[c8] = (f32x4){0.f, 0.f, 0.f, 0.f};

  int cur = 0;
  stage(0, 0, 0);
  __syncthreads();

  for (int h = 0; h < 8; h++) {
    const bf16_t* qp = q + (size_t)(b * 1024 + qg0 + l16) * 512 + h * 64 + 8 * g;
    bf16x8 aq0 = *(const bf16x8*)qp;
    bf16x8 aq1 = *(const bf16x8*)(qp + 32);
    float CR[4];
#pragma unroll
    for (int j = 0; j < 4; j++) CR[j] = crl[(b * 8 + h) * 1024 + qg0 + g * 4 + j];
#pragma unroll
    for (int kt = 0; kt < 2; kt++) {
      if (kt == 0) stage(cur ^ 1, 1, h);
      else if (h < 7) stage(cur ^ 1, 0, h + 1);
      const char* cK = (const char*)&ldsK[0][0] + cur * 8192;
#pragma unroll
      for (int cg = 0; cg < 4; cg++) {
        const char* krow = cK + ((cg * 16 + l16) << 7);
        bf16x8 k0 = *(const bf16x8*)(krow + ((g ^ rph) << 4));
        bf16x8 k1 = *(const bf16x8*)(krow + (((g + 4) ^ rph) << 4));
        f32x4 s = (f32x4){0.f, 0.f, 0.f, 0.f};
        s = mfma16(aq0, k0, s);
        s = mfma16(aq1, k1, s);
#pragma unroll
        for (int j = 0; j < 4; j++)
          macc[kt * 4 + cg][j] += __expf(s[j] + av[kt * 4 + cg][j] - CR[j]);
      }
      __syncthreads();
      cur ^= 1;
    }
  }

#pragma unroll
  for (int c8 = 0; c8 < 8; c8++)
#pragma unroll
    for (int j = 0; j < 4; j++)
      mout[(size_t)(b * 1024 + qg0 + g * 4 + j) * 1024 + kbase + c8 * 16 + l16] =
          macc[c8][j] * 0.125f;
}

extern "C" void kernel_launch(void* const* d_in, const int* in_sizes, int n_in,
                              void* d_out, int out_size, void* d_ws, size_t ws_size,
                              hipStream_t stream) {
  (void)in_sizes; (void)n_in; (void)out_size; (void)ws_size;
  const float* x   = (const float*)d_in[0];
  const float* adj = (const float*)d_in[1];
  const int*   msk = (const int*)d_in[2];
  const float* Wq  = (const float*)d_in[3];
  const float* Wk  = (const float*)d_in[4];
  const float* Wv  = (const float*)d_in[5];
  const float* Wo  = (const float*)d_in[6];
  const float* W1  = (const float*)d_in[7];
  const float* b1  = (const float*)d_in[8];
  const float* W2  = (const float*)d_in[9];
  const float* b2  = (const float*)d_in[10];
  const float* g1  = (const float*)d_in[11];
  const float* be1 = (const float*)d_in[12];
  const float* g2  = (const float*)d_in[13];
  const float* be2 = (const float*)d_in[14];

  float* out  = (float*)d_out;
  float* mout = out + (size_t)8 * 1024 * 512;

  char* ws = (char*)d_ws;
  const size_t MB = 1024 * 1024;
  bf16_t* wqb = (bf16_t*)(ws);
  bf16_t* wkb = (bf16_t*)(ws + 512 * 1024);
  bf16_t* wvb = (bf16_t*)(ws + 1 * MB);
  bf16_t* wob = (bf16_t*)(ws + 3 * MB / 2);
  bf16_t* w1b = (bf16_t*)(ws + 2 * MB);
  bf16_t* w2b = (bf16_t*)(ws + 4 * MB);
  float*  Cb   = (float*)(ws + 6 * MB);              // 256 KB
  float*  crl  = (float*)(ws + 6 * MB + 256 * 1024); // 256 KB (C + ln l)
  float*  amax = (float*)(ws + 6 * MB + 512 * 1024); // 4 KB
  float*  kmax = (float*)(ws + 6 * MB + 768 * 1024); // 256 B
  float*  lp   = (float*)(ws + 7 * MB);              // 512 KB
  bf16_t* xb   = (bf16_t*)(ws + 8 * MB);   // 8-16: x bf16; then ctx; then zb
  bf16_t* ctx  = xb;
  bf16_t* zb   = xb;
  bf16_t* qb   = (bf16_t*)(ws + 16 * MB);  // 16-24
  bf16_t* kb   = (bf16_t*)(ws + 24 * MB);  // 24-32
  bf16_t* vb   = (bf16_t*)(ws + 32 * MB);  // 32-40 (dead after vtrans)
  bf16_t* ctxp1 = vb;
  bf16_t* vT   = (bf16_t*)(ws + 40 * MB);  // 40-48
  bf16_t* ctxp0 = (bf16_t*)(ws + 48 * MB); // 48-56
  float*  gout1 = (float*)(ws + 16 * MB);  // 16-32 f32 (wo-gemm -> resln1)
  bf16_t* hb    = (bf16_t*)(ws + 16 * MB); // 16-48 bf16 (ffn1 -> ffn2)
  float*  gout2 = (float*)(ws + 48 * MB);  // 48-64 f32 (ffn2 -> resln2)
  float*  adjm  = (float*)(ws + 72 * MB);  // 72-76

  // converts
  k_cvt<<<4096, 256, 0, stream>>>(x,  xb,  1048576);
  k_cvt<<<256,  256, 0, stream>>>(Wq, wqb, 65536);
  k_cvt<<<256,  256, 0, stream>>>(Wk, wkb, 65536);
  k_cvt<<<256,  256, 0, stream>>>(Wv, wvb, 65536);
  k_cvt<<<256,  256, 0, stream>>>(Wo, wob, 65536);
  k_cvt<<<1024, 256, 0, stream>>>(W1, w1b, 262144);
  k_cvt<<<1024, 256, 0, stream>>>(W2, w2b, 262144);

  k_prep<<<256, 256, 0, stream>>>(adj, msk, adjm, amax);

  // QKV: one GEMM, N=1536 (wq|wk|wv contiguous); q output pre-scaled by 0.125
  k_gemm<0><<<64 * 24, 256, 0, stream>>>(xb, wqb, 512, 24, nullptr, qb, nullptr, 512);
  k_vtrans<<<1024, 256, 0, stream>>>(vb, vT);
  k_knorm<<<64, 256, 0, stream>>>(kb, kmax);
  k_cbound<<<256, 256, 0, stream>>>(qb, kmax, amax, Cb);

  // attention: partials (k-split x2), combine (-> ctx, crl), mean
  k_attn_ctx<<<2048, 256, 0, stream>>>(qb, kb, vT, adjm, Cb, lp, ctxp0, ctxp1);
  k_attn_fin<<<4096, 256, 0, stream>>>(ctxp0, ctxp1, lp, Cb, ctx, crl);
  k_attn_mean<<<1024, 256, 0, stream>>>(qb, kb, adjm, crl, mout);

  // Wo proj -> gout1 ; residual(x f32) + LN1 -> zb (bf16)
  k_gemm<2><<<64 * 8, 256, 0, stream>>>(ctx, wob, 512, 8, nullptr, nullptr, gout1, 512);
  k_resln<<<2048, 256, 0, stream>>>(gout1, x, nullptr, g1, be1, nullptr, zb);
  // FFN1: relu(zb @ W1^T + b1) -> hb
  k_gemm<1><<<64 * 32, 256, 0, stream>>>(zb, w1b, 512, 32, b1, hb, nullptr, 2048);
  // FFN2 -> gout2 ; residual(zb bf16) + LN2 -> out
  k_gemm<2><<<64 * 8, 256, 0, stream>>>(hb, w2b, 2048, 8, b2, nullptr, gout2, 512);
  k_resln<<<2048, 256, 0, stream>>>(gout2, nullptr, zb, g2, be2, out, nullptr);
}

// Round 6
// 271.962 us; speedup vs baseline: 1.7873x; 1.0288x over previous
//
#include <hip/hip_runtime.h>
#include <math.h>
#include <stdint.h>

// GraphTransformerLayer on MI355X (gfx950).
// B=8, N=1024, D=512, H=8, Dh=64, F=2048.
// Round 6: attn_mean — factor exp(adj) out of the h-sum (adjm only touched in
//          a per-kt epilogue), kt-outer/h-inner loop -> VGPR 184 -> ~90 for
//          occupancy; fused weight-convert launch.

using bf16_t = __bf16;
typedef __attribute__((__ext_vector_type__(8))) __bf16 bf16x8;
typedef __attribute__((__ext_vector_type__(4))) __bf16 bf16x4;
typedef __attribute__((__ext_vector_type__(4))) float  f32x4;

#define DEVI __device__ __forceinline__

DEVI f32x4 mfma16(bf16x8 a, bf16x8 b, f32x4 c) {
  return __builtin_amdgcn_mfma_f32_16x16x32_bf16(a, b, c, 0, 0, 0);
}

// async global->LDS, 16B per lane. dest = wave-uniform base (+ lane*16 by HW).
DEVI void gload_lds16(const void* g, void* l) {
  __builtin_amdgcn_global_load_lds(
      (const __attribute__((address_space(1))) uint32_t*)g,
      (__attribute__((address_space(3))) uint32_t*)l, 16, 0, 0);
}

#define NEGC  (-1.0e9f)
#define EPSC  (1e-5f)

// ---------------- f32 -> bf16 convert (vector4) ----------------
__global__ __launch_bounds__(256) void k_cvt(const float* __restrict__ in,
                                             bf16_t* __restrict__ out, int n4) {
  int i = blockIdx.x * 256 + threadIdx.x;
  if (i < n4) {
    float4 v = ((const float4*)in)[i];
    bf16x4 o = { (__bf16)v.x, (__bf16)v.y, (__bf16)v.z, (__bf16)v.w };
    ((bf16x4*)out)[i] = o;
  }
}

// ---------------- fused weight converts (Wq,Wk,Wv,Wo: 256 blks each; W1,W2: 1024) ----
__global__ __launch_bounds__(256) void k_cvtw(const float* __restrict__ wq,
                                              const float* __restrict__ wk,
                                              const float* __restrict__ wv,
                                              const float* __restrict__ wo,
                                              const float* __restrict__ w1,
                                              const float* __restrict__ w2,
                                              bf16_t* __restrict__ owq,
                                              bf16_t* __restrict__ owk,
                                              bf16_t* __restrict__ owv,
                                              bf16_t* __restrict__ owo,
                                              bf16_t* __restrict__ ow1,
                                              bf16_t* __restrict__ ow2) {
  int blk = blockIdx.x;
  const float* src; bf16_t* dst; int base;
  if      (blk < 256)  { src = wq; dst = owq; base = blk; }
  else if (blk < 512)  { src = wk; dst = owk; base = blk - 256; }
  else if (blk < 768)  { src = wv; dst = owv; base = blk - 512; }
  else if (blk < 1024) { src = wo; dst = owo; base = blk - 768; }
  else if (blk < 2048) { src = w1; dst = ow1; base = blk - 1024; }
  else                 { src = w2; dst = ow2; base = blk - 2048; }
  int i = base * 256 + threadIdx.x;
  float4 v = ((const float4*)src)[i];
  bf16x4 o = { (__bf16)v.x, (__bf16)v.y, (__bf16)v.z, (__bf16)v.w };
  ((bf16x4*)dst)[i] = o;
}

// ---------------- adjm = mask ? adj : NEG ; rowmax of masked adj ----------------
__global__ __launch_bounds__(256) void k_prep(const float* __restrict__ adj,
                                              const int* __restrict__ msk,
                                              float* __restrict__ adjm,
                                              float* __restrict__ rowmax) {
  int row  = blockIdx.x * 4 + (threadIdx.x >> 6);
  int lane = threadIdx.x & 63;
  float m = -INFINITY;
  for (int i = 0; i < 16; i++) {
    int c = lane + 64 * i;
    size_t idx = (size_t)row * 1024 + c;
    float a = adj[idx];
    bool valid = (msk[idx] != 0);
    adjm[idx] = valid ? a : NEGC;
    if (valid) m = fmaxf(m, a);
  }
  for (int off = 1; off < 64; off <<= 1) m = fmaxf(m, __shfl_xor(m, off));
  if (lane == 0) rowmax[row] = m;
}

// ---------------- tiled GEMM: C[8192 x N] = A[8192 x K] @ B[N x K]^T ----------------
// 128x64 tile, 4 waves (2x2), each wave 64x32 (4x2 fragments). BK=32.
// Double-buffered global_load_lds staging, 16B-block XOR swizzle (blk ^= row&3).
// EPI: 0 = bf16 store with which-routing (which==0 scaled by 0.125 for q),
//      1 = bf16 bias+relu, 2 = f32 (+opt bias).
template<int EPI>
__global__ __launch_bounds__(256) void k_gemm(const bf16_t* __restrict__ A,
                                              const bf16_t* __restrict__ B,
                                              int K, int nbx,
                                              const float* __restrict__ bias,
                                              bf16_t* __restrict__ outb,
                                              float* __restrict__ outf,
                                              int out_ncols) {
  __shared__ bf16_t lA[2][4096];   // [128][32] bf16, 8KB per buf
  __shared__ bf16_t lB[2][2048];   // [64][32]  bf16, 4KB per buf
  int bid = blockIdx.x;
  int nb = bid % nbx, mb = bid / nbx;
  int tid = threadIdx.x, wid = tid >> 6, lane = tid & 63;
  int l16 = lane & 15, g = lane >> 4;
  int wr = wid >> 1, wc = wid & 1;
  int rowbase = mb * 128, c0 = nb * 64;

  int dA0 = wid * 2048 + lane * 16;
  int rA0 = dA0 >> 6, rA1 = (dA0 + 1024) >> 6;
  int bA  = (dA0 >> 4) & 3;
  const bf16_t* Asrc0 = A + (size_t)(rowbase + rA0) * K + (bA ^ (rA0 & 3)) * 8;
  const bf16_t* Asrc1 = A + (size_t)(rowbase + rA1) * K + (bA ^ (rA1 & 3)) * 8;
  int dB = wid * 1024 + lane * 16;
  int rB = dB >> 6, bB = (dB >> 4) & 3;
  const bf16_t* Bsrc = B + (size_t)(c0 + rB) * K + (bB ^ (rB & 3)) * 8;

  f32x4 acc[4][2];
#pragma unroll
  for (int m = 0; m < 4; m++)
#pragma unroll
    for (int n = 0; n < 2; n++) acc[m][n] = (f32x4){0.f, 0.f, 0.f, 0.f};

  gload_lds16(Asrc0, &lA[0][wid * 1024]);
  gload_lds16(Asrc1, &lA[0][wid * 1024 + 512]);
  gload_lds16(Bsrc, &lB[0][wid * 512]);
  __syncthreads();

  for (int k0 = 0; k0 < K; k0 += 32) {
    int buf = (k0 >> 5) & 1;
    if (k0 + 32 < K) {
      gload_lds16(Asrc0 + k0 + 32, &lA[buf ^ 1][wid * 1024]);
      gload_lds16(Asrc1 + k0 + 32, &lA[buf ^ 1][wid * 1024 + 512]);
      gload_lds16(Bsrc + k0 + 32, &lB[buf ^ 1][wid * 512]);
    }
    const char* cA = (const char*)lA[buf];
    const char* cB = (const char*)lB[buf];
    bf16x8 af[4], bq[2];
#pragma unroll
    for (int m = 0; m < 4; m++) {
      int row = wr * 64 + m * 16 + l16;
      af[m] = *(const bf16x8*)(cA + row * 64 + ((g ^ (row & 3)) << 4));
    }
#pragma unroll
    for (int n = 0; n < 2; n++) {
      int row = wc * 32 + n * 16 + l16;
      bq[n] = *(const bf16x8*)(cB + row * 64 + ((g ^ (row & 3)) << 4));
    }
#pragma unroll
    for (int m = 0; m < 4; m++)
#pragma unroll
      for (int n = 0; n < 2; n++) acc[m][n] = mfma16(af[m], bq[n], acc[m][n]);
    __syncthreads();
  }

  int which = c0 / out_ncols;
  int cloc0 = c0 - which * out_ncols;
  size_t obase = (size_t)which * 8192 * out_ncols;
  float osc = (EPI == 0 && which == 0) ? 0.125f : 1.0f;  // q pre-scale
#pragma unroll
  for (int n = 0; n < 2; n++) {
    int col = cloc0 + wc * 32 + n * 16 + l16;
    float bv = (EPI >= 1 && bias) ? bias[col] : 0.f;
#pragma unroll
    for (int m = 0; m < 4; m++)
#pragma unroll
      for (int j = 0; j < 4; j++) {
        int row = rowbase + wr * 64 + m * 16 + g * 4 + j;
        float v = acc[m][n][j] + bv;
        size_t idx = obase + (size_t)row * out_ncols + col;
        if (EPI == 1) outb[idx] = (__bf16)fmaxf(v, 0.f);
        else if (EPI == 0) outb[idx] = (__bf16)(v * osc);
        else outf[idx] = v;
      }
  }
}

// ---------------- residual + LayerNorm (memory-bound): rows of 512 ----------------
__global__ __launch_bounds__(256) void k_resln(const float* __restrict__ gin,
                                               const float* __restrict__ residf,
                                               const bf16_t* __restrict__ residb,
                                               const float* __restrict__ gam,
                                               const float* __restrict__ bet,
                                               float* __restrict__ outf,
                                               bf16_t* __restrict__ outb) {
  int row = blockIdx.x * 4 + (threadIdx.x >> 6);
  int lane = threadIdx.x & 63;
  const float* gp = gin + (size_t)row * 512;
  float4 a0 = ((const float4*)gp)[lane];
  float4 a1 = ((const float4*)gp)[lane + 64];
  if (residf) {
    const float* rp = residf + (size_t)row * 512;
    float4 r0 = ((const float4*)rp)[lane];
    float4 r1 = ((const float4*)rp)[lane + 64];
    a0.x += r0.x; a0.y += r0.y; a0.z += r0.z; a0.w += r0.w;
    a1.x += r1.x; a1.y += r1.y; a1.z += r1.z; a1.w += r1.w;
  } else {
    const bf16_t* rp = residb + (size_t)row * 512;
    bf16x4 r0 = ((const bf16x4*)rp)[lane];
    bf16x4 r1 = ((const bf16x4*)rp)[lane + 64];
    a0.x += (float)r0[0]; a0.y += (float)r0[1]; a0.z += (float)r0[2]; a0.w += (float)r0[3];
    a1.x += (float)r1[0]; a1.y += (float)r1[1]; a1.z += (float)r1[2]; a1.w += (float)r1[3];
  }
  float s = a0.x + a0.y + a0.z + a0.w + a1.x + a1.y + a1.z + a1.w;
  for (int off = 1; off < 64; off <<= 1) s += __shfl_xor(s, off);
  float mu = s * (1.f / 512.f);
  float sq = (a0.x - mu) * (a0.x - mu) + (a0.y - mu) * (a0.y - mu) +
             (a0.z - mu) * (a0.z - mu) + (a0.w - mu) * (a0.w - mu) +
             (a1.x - mu) * (a1.x - mu) + (a1.y - mu) * (a1.y - mu) +
             (a1.z - mu) * (a1.z - mu) + (a1.w - mu) * (a1.w - mu);
  for (int off = 1; off < 64; off <<= 1) sq += __shfl_xor(sq, off);
  float rs = rsqrtf(sq * (1.f / 512.f) + EPSC);

  float4 g0 = ((const float4*)gam)[lane], g1v = ((const float4*)gam)[lane + 64];
  float4 b0 = ((const float4*)bet)[lane], b1v = ((const float4*)bet)[lane + 64];
  float4 o0, o1;
  o0.x = (a0.x - mu) * rs * g0.x + b0.x;  o0.y = (a0.y - mu) * rs * g0.y + b0.y;
  o0.z = (a0.z - mu) * rs * g0.z + b0.z;  o0.w = (a0.w - mu) * rs * g0.w + b0.w;
  o1.x = (a1.x - mu) * rs * g1v.x + b1v.x; o1.y = (a1.y - mu) * rs * g1v.y + b1v.y;
  o1.z = (a1.z - mu) * rs * g1v.z + b1v.z; o1.w = (a1.w - mu) * rs * g1v.w + b1v.w;
  if (outf) {
    float* op = outf + (size_t)row * 512;
    ((float4*)op)[lane] = o0;
    ((float4*)op)[lane + 64] = o1;
  }
  if (outb) {
    bf16_t* op = outb + (size_t)row * 512;
    bf16x4 q0 = { (__bf16)o0.x, (__bf16)o0.y, (__bf16)o0.z, (__bf16)o0.w };
    bf16x4 q1 = { (__bf16)o1.x, (__bf16)o1.y, (__bf16)o1.z, (__bf16)o1.w };
    ((bf16x4*)op)[lane] = q0;
    ((bf16x4*)op)[lane + 64] = q1;
  }
}

// ---------------- v transpose: [B,N,H*64] -> vT [B,H,64,N] ----------------
__global__ __launch_bounds__(256) void k_vtrans(const bf16_t* __restrict__ v,
                                                bf16_t* __restrict__ vT) {
  int bid = blockIdx.x;
  int nt = bid & 15, h = (bid >> 4) & 7, b = bid >> 7;
  __shared__ bf16_t t[64 * 66];
  int tid = threadIdx.x, wid = tid >> 6, lane = tid & 63;
  for (int i = 0; i < 16; i++) {
    int n = wid * 16 + i;
    t[lane * 66 + n] = v[(size_t)(b * 1024 + nt * 64 + n) * 512 + h * 64 + lane];
  }
  __syncthreads();
  for (int i = 0; i < 16; i++) {
    int d = wid * 16 + i;
    vT[(size_t)((b * 8 + h) * 64 + d) * 1024 + nt * 64 + lane] = t[d * 66 + lane];
  }
}

// ---------------- max_n |k[b,h,n,:]| ----------------
__global__ __launch_bounds__(256) void k_knorm(const bf16_t* __restrict__ kk,
                                               float* __restrict__ kmax) {
  int bh = blockIdx.x;
  int b = bh >> 3, h = bh & 7;
  int tid = threadIdx.x;
  float mx = 0.f;
  for (int n = tid; n < 1024; n += 256) {
    const bf16_t* kp = kk + (size_t)(b * 1024 + n) * 512 + h * 64;
    float ss = 0.f;
#pragma unroll
    for (int vv = 0; vv < 8; vv++) {
      bf16x8 kv = *(const bf16x8*)(kp + vv * 8);
#pragma unroll
      for (int e = 0; e < 8; e++) { float f = (float)kv[e]; ss += f * f; }
    }
    mx = fmaxf(mx, ss);
  }
  for (int off = 1; off < 64; off <<= 1) mx = fmaxf(mx, __shfl_xor(mx, off));
  __shared__ float red[4];
  if ((tid & 63) == 0) red[tid >> 6] = mx;
  __syncthreads();
  if (tid == 0) kmax[bh] = sqrtf(fmaxf(fmaxf(red[0], red[1]), fmaxf(red[2], red[3])));
}

// ---------------- score upper bound C[b,h,n] = |q'| * kmax + rowmax(adj) ----------------
__global__ __launch_bounds__(256) void k_cbound(const bf16_t* __restrict__ q,
                                                const float* __restrict__ kmax,
                                                const float* __restrict__ rowmax,
                                                float* __restrict__ Cb) {
  int t = blockIdx.x * 256 + threadIdx.x;  // (b*8+h)*1024 + n
  int b = t >> 13, h = (t >> 10) & 7, n = t & 1023;
  const bf16_t* qp = q + (size_t)(b * 1024 + n) * 512 + h * 64;
  float ss = 0.f;
#pragma unroll
  for (int vv = 0; vv < 8; vv++) {
    bf16x8 kv = *(const bf16x8*)(qp + vv * 8);
#pragma unroll
    for (int e = 0; e < 8; e++) { float f = (float)kv[e]; ss += f * f; }
  }
  float am = rowmax[n];
  Cb[t] = (am < -1e30f) ? 0.f : (sqrtf(ss) * kmax[b * 8 + h] + am);
}

// ---------------- attention partial: un-normalized ctx partial + partial l ----------------
__global__ __launch_bounds__(256) void k_attn_ctx(const bf16_t* __restrict__ q,
                                                  const bf16_t* __restrict__ kk,
                                                  const bf16_t* __restrict__ vT,
                                                  const float* __restrict__ adjm,
                                                  const float* __restrict__ Cb,
                                                  float* __restrict__ lp,
                                                  bf16_t* __restrict__ ctxp0,
                                                  bf16_t* __restrict__ ctxp1) {
  __shared__ bf16_t ldsK[2][4096];
  __shared__ bf16_t ldsV[2][4096];
  __shared__ bf16_t pt[4][16 * 72];
  int bid = blockIdx.x;
  int split = bid & 1, qt = (bid >> 1) & 15, h = (bid >> 5) & 7, b = bid >> 8;
  int tid = threadIdx.x, wid = tid >> 6, lane = tid & 63;
  int l16 = lane & 15, g = lane >> 4;
  int qg0 = qt * 64 + wid * 16;
  bf16_t* ctxp = split ? ctxp1 : ctxp0;
  int kvbase = (b * 8 + h) * 64;

  int d0 = wid * 2048 + lane * 16;
  int row0 = d0 >> 7, row1 = (d0 + 1024) >> 7;
  int cb0 = ((d0 >> 4) & 7) ^ (row0 & 7);
  int cb1 = ((d0 >> 4) & 7) ^ (row1 & 7);
  const bf16_t* ksrc = kk + (size_t)(b * 1024) * 512 + h * 64;
  const bf16_t* vsrc = vT + (size_t)kvbase * 1024;

  auto stage = [&](int buf, int kc0) {
    gload_lds16(ksrc + (size_t)(kc0 + row0) * 512 + cb0 * 8, &ldsK[buf][wid * 1024]);
    gload_lds16(ksrc + (size_t)(kc0 + row1) * 512 + cb1 * 8, &ldsK[buf][wid * 1024 + 512]);
    gload_lds16(vsrc + (size_t)row0 * 1024 + kc0 + cb0 * 8, &ldsV[buf][wid * 1024]);
    gload_lds16(vsrc + (size_t)row1 * 1024 + kc0 + cb1 * 8, &ldsV[buf][wid * 1024 + 512]);
  };

  const bf16_t* qp = q + (size_t)(b * 1024 + qg0 + l16) * 512 + h * 64 + 8 * g;
  bf16x8 aq0 = *(const bf16x8*)qp;
  bf16x8 aq1 = *(const bf16x8*)(qp + 32);

  float Cj[4];
#pragma unroll
  for (int j = 0; j < 4; j++) Cj[j] = Cb[(b * 8 + h) * 1024 + qg0 + g * 4 + j];

  f32x4 cacc[4];
#pragma unroll
  for (int d = 0; d < 4; d++) cacc[d] = (f32x4){0.f, 0.f, 0.f, 0.f};
  float ls[4] = {0.f, 0.f, 0.f, 0.f};
  bf16_t* myp = pt[wid];
  int rph = l16 & 7;

  int ktS = split * 8, ktE = ktS + 8;
  stage(0, ktS * 64);
  __syncthreads();

  for (int kt = ktS; kt < ktE; ++kt) {
    int buf = (kt - ktS) & 1;
    int kc0 = kt * 64;
    int ktn = (kt + 1 < ktE) ? kt + 1 : kt;
    stage(buf ^ 1, ktn * 64);

    float am[4][4];
#pragma unroll
    for (int cg = 0; cg < 4; cg++)
#pragma unroll
      for (int j = 0; j < 4; j++)
        am[cg][j] = adjm[(size_t)(qg0 + g * 4 + j) * 1024 + kc0 + cg * 16 + l16];

    const char* curK = (const char*)ldsK[buf];
    const char* curV = (const char*)ldsV[buf];

#pragma unroll
    for (int cg = 0; cg < 4; cg++) {
      const char* krow = curK + ((cg * 16 + l16) << 7);
      bf16x8 k0 = *(const bf16x8*)(krow + ((g ^ rph) << 4));
      bf16x8 k1 = *(const bf16x8*)(krow + (((g + 4) ^ rph) << 4));
      f32x4 s = (f32x4){0.f, 0.f, 0.f, 0.f};
      s = mfma16(aq0, k0, s);
      s = mfma16(aq1, k1, s);
#pragma unroll
      for (int j = 0; j < 4; j++) {
        float sv = s[j] + am[cg][j];
        float p = __expf(sv - Cj[j]);
        ls[j] += p;
        myp[(g * 4 + j) * 72 + cg * 16 + l16] = (__bf16)p;
      }
    }
#pragma unroll
    for (int half = 0; half < 2; half++) {
      bf16x8 pa = *(const bf16x8*)(myp + l16 * 72 + half * 32 + 8 * g);
#pragma unroll
      for (int dg = 0; dg < 4; dg++) {
        const char* vrow = curV + ((dg * 16 + l16) << 7);
        bf16x8 vv = *(const bf16x8*)(vrow + (((g + half * 4) ^ rph) << 4));
        cacc[dg] = mfma16(pa, vv, cacc[dg]);
      }
    }
    __syncthreads();
  }

#pragma unroll
  for (int j = 0; j < 4; j++)
    for (int off = 1; off < 16; off <<= 1) ls[j] += __shfl_xor(ls[j], off);

#pragma unroll
  for (int dg = 0; dg < 4; dg++)
#pragma unroll
    for (int j = 0; j < 4; j++) {
      int row = qg0 + g * 4 + j;
      ctxp[(size_t)(b * 1024 + row) * 512 + h * 64 + dg * 16 + l16] = (__bf16)cacc[dg][j];
    }
  if (l16 == 0) {
#pragma unroll
    for (int j = 0; j < 4; j++)
      lp[split * 65536 + (b * 8 + h) * 1024 + qg0 + g * 4 + j] = ls[j];
  }
}

// ---------------- combine partials -> ctx bf16, crl = C + ln(l) ----------------
__global__ __launch_bounds__(256) void k_attn_fin(const bf16_t* __restrict__ ctxp0,
                                                  const bf16_t* __restrict__ ctxp1,
                                                  const float* __restrict__ lp,
                                                  const float* __restrict__ Cb,
                                                  bf16_t* __restrict__ ctx,
                                                  float* __restrict__ crl) {
  int t = blockIdx.x * 256 + threadIdx.x;  // 1048576 groups of 4 elems
  int col4 = t & 127, row = t >> 7;
  int b = row >> 10, qq = row & 1023, h = col4 >> 4;
  int li = (b * 8 + h) * 1024 + qq;
  float l = lp[li] + lp[65536 + li];
  float rc = (l > 0.f) ? (1.f / l) : 0.f;
  bf16x4 p0 = ((const bf16x4*)ctxp0)[t];
  bf16x4 p1 = ((const bf16x4*)ctxp1)[t];
  bf16x4 o;
#pragma unroll
  for (int i = 0; i < 4; i++) o[i] = (__bf16)(((float)p0[i] + (float)p1[i]) * rc);
  ((bf16x4*)ctx)[t] = o;
  if ((col4 & 15) == 0)
    crl[li] = (l > 0.f) ? (Cb[li] + __logf(l)) : 1.0e30f;
}

// ---------------- attention mean over heads -> mout ----------------
// grid 1024: bid = kq(3) | qt(4) | b(3). Block: 64 q (4 waves x 16) x 128 k.
// kt outer (2 sub-tiles of 64k), h inner (8); mean = exp(adj) * sum_h exp(s - CR):
// adjm only touched in the per-kt epilogue -> low VGPR.
__global__ __launch_bounds__(256) void k_attn_mean(const bf16_t* __restrict__ q,
                                                   const bf16_t* __restrict__ kk,
                                                   const float* __restrict__ adjm,
                                                   const float* __restrict__ crl,
                                                   float* __restrict__ mout) {
  __shared__ bf16_t ldsK[2][4096];
  int bid = blockIdx.x;
  int kq = bid & 7, qt = (bid >> 3) & 15, b = bid >> 7;
  int tid = threadIdx.x, wid = tid >> 6, lane = tid & 63;
  int l16 = lane & 15, g = lane >> 4;
  int qg0 = qt * 64 + wid * 16;
  int kbase = kq * 128;
  int rph = l16 & 7;

  int d0 = wid * 2048 + lane * 16;
  int row0 = d0 >> 7, row1 = (d0 + 1024) >> 7;
  int cb0 = ((d0 >> 4) & 7) ^ (row0 & 7);
  int cb1 = ((d0 >> 4) & 7) ^ (row1 & 7);
  const bf16_t* ksrc = kk + (size_t)(b * 1024) * 512;

  auto stage = [&](int buf, int kt, int h) {
    gload_lds16(ksrc + (size_t)(kbase + kt * 64 + row0) * 512 + h * 64 + cb0 * 8,
                (char*)&ldsK[0][0] + buf * 8192 + wid * 2048);
    gload_lds16(ksrc + (size_t)(kbase + kt * 64 + row1) * 512 + h * 64 + cb1 * 8,
                (char*)&ldsK[0][0] + buf * 8192 + wid * 2048 + 1024);
  };

  stage(0, 0, 0);
  __syncthreads();

  for (int kt = 0; kt < 2; kt++) {
    f32x4 macc[4];
#pragma unroll
    for (int cg = 0; cg < 4; cg++) macc[cg] = (f32x4){0.f, 0.f, 0.f, 0.f};

    for (int h = 0; h < 8; h++) {
      int t = kt * 8 + h, cur = t & 1;
      if (t < 15) { int nt = t + 1; stage(cur ^ 1, nt >> 3, nt & 7); }
      const bf16_t* qp = q + (size_t)(b * 1024 + qg0 + l16) * 512 + h * 64 + 8 * g;
      bf16x8 aq0 = *(const bf16x8*)qp;
      bf16x8 aq1 = *(const bf16x8*)(qp + 32);
      float CR[4];
#pragma unroll
      for (int j = 0; j < 4; j++) CR[j] = crl[(b * 8 + h) * 1024 + qg0 + g * 4 + j];
      const char* cK = (const char*)&ldsK[0][0] + cur * 8192;
#pragma unroll
      for (int cg = 0; cg < 4; cg++) {
        const char* krow = cK + ((cg * 16 + l16) << 7);
        bf16x8 k0 = *(const bf16x8*)(krow + ((g ^ rph) << 4));
        bf16x8 k1 = *(const bf16x8*)(krow + (((g + 4) ^ rph) << 4));
        f32x4 s = (f32x4){0.f, 0.f, 0.f, 0.f};
        s = mfma16(aq0, k0, s);
        s = mfma16(aq1, k1, s);
#pragma unroll
        for (int j = 0; j < 4; j++)
          macc[cg][j] += __expf(s[j] - CR[j]);
      }
      __syncthreads();
    }

    // epilogue for this kt: multiply by exp(adj)/8 and store
#pragma unroll
    for (int cg = 0; cg < 4; cg++)
#pragma unroll
      for (int j = 0; j < 4; j++) {
        size_t off = (size_t)(qg0 + g * 4 + j) * 1024 + kbase + kt * 64 + cg * 16 + l16;
        float a = adjm[off];
        mout[(size_t)b * 1048576 + off] = macc[cg][j] * __expf(a) * 0.125f;
      }
  }
}

extern "C" void kernel_launch(void* const* d_in, const int* in_sizes, int n_in,
                              void* d_out, int out_size, void* d_ws, size_t ws_size,
                              hipStream_t stream) {
  (void)in_sizes; (void)n_in; (void)out_size; (void)ws_size;
  const float* x   = (const float*)d_in[0];
  const float* adj = (const float*)d_in[1];
  const int*   msk = (const int*)d_in[2];
  const float* Wq  = (const float*)d_in[3];
  const float* Wk  = (const float*)d_in[4];
  const float* Wv  = (const float*)d_in[5];
  const float* Wo  = (const float*)d_in[6];
  const float* W1  = (const float*)d_in[7];
  const float* b1  = (const float*)d_in[8];
  const float* W2  = (const float*)d_in[9];
  const float* b2  = (const float*)d_in[10];
  const float* g1  = (const float*)d_in[11];
  const float* be1 = (const float*)d_in[12];
  const float* g2  = (const float*)d_in[13];
  const float* be2 = (const float*)d_in[14];

  float* out  = (float*)d_out;
  float* mout = out + (size_t)8 * 1024 * 512;

  char* ws = (char*)d_ws;
  const size_t MB = 1024 * 1024;
  bf16_t* wqb = (bf16_t*)(ws);
  bf16_t* wkb = (bf16_t*)(ws + 512 * 1024);
  bf16_t* wvb = (bf16_t*)(ws + 1 * MB);
  bf16_t* wob = (bf16_t*)(ws + 3 * MB / 2);
  bf16_t* w1b = (bf16_t*)(ws + 2 * MB);
  bf16_t* w2b = (bf16_t*)(ws + 4 * MB);
  float*  Cb   = (float*)(ws + 6 * MB);              // 256 KB
  float*  crl  = (float*)(ws + 6 * MB + 256 * 1024); // 256 KB (C + ln l)
  float*  amax = (float*)(ws + 6 * MB + 512 * 1024); // 4 KB
  float*  kmax = (float*)(ws + 6 * MB + 768 * 1024); // 256 B
  float*  lp   = (float*)(ws + 7 * MB);              // 512 KB
  bf16_t* xb   = (bf16_t*)(ws + 8 * MB);   // 8-16: x bf16; then ctx; then zb
  bf16_t* ctx  = xb;
  bf16_t* zb   = xb;
  bf16_t* qb   = (bf16_t*)(ws + 16 * MB);  // 16-24
  bf16_t* kb   = (bf16_t*)(ws + 24 * MB);  // 24-32
  bf16_t* vb   = (bf16_t*)(ws + 32 * MB);  // 32-40 (dead after vtrans)
  bf16_t* ctxp1 = vb;
  bf16_t* vT   = (bf16_t*)(ws + 40 * MB);  // 40-48
  bf16_t* ctxp0 = (bf16_t*)(ws + 48 * MB); // 48-56
  float*  gout1 = (float*)(ws + 16 * MB);  // 16-32 f32 (wo-gemm -> resln1)
  bf16_t* hb    = (bf16_t*)(ws + 16 * MB); // 16-48 bf16 (ffn1 -> ffn2)
  float*  gout2 = (float*)(ws + 48 * MB);  // 48-64 f32 (ffn2 -> resln2)
  float*  adjm  = (float*)(ws + 72 * MB);  // 72-76

  // converts
  k_cvt<<<4096, 256, 0, stream>>>(x, xb, 1048576);
  k_cvtw<<<3072, 256, 0, stream>>>(Wq, Wk, Wv, Wo, W1, W2,
                                   wqb, wkb, wvb, wob, w1b, w2b);

  k_prep<<<256, 256, 0, stream>>>(adj, msk, adjm, amax);

  // QKV: one GEMM, N=1536 (wq|wk|wv contiguous); q output pre-scaled by 0.125
  k_gemm<0><<<64 * 24, 256, 0, stream>>>(xb, wqb, 512, 24, nullptr, qb, nullptr, 512);
  k_vtrans<<<1024, 256, 0, stream>>>(vb, vT);
  k_knorm<<<64, 256, 0, stream>>>(kb, kmax);
  k_cbound<<<256, 256, 0, stream>>>(qb, kmax, amax, Cb);

  // attention: partials (k-split x2), combine (-> ctx, crl), mean
  k_attn_ctx<<<2048, 256, 0, stream>>>(qb, kb, vT, adjm, Cb, lp, ctxp0, ctxp1);
  k_attn_fin<<<4096, 256, 0, stream>>>(ctxp0, ctxp1, lp, Cb, ctx, crl);
  k_attn_mean<<<1024, 256, 0, stream>>>(qb, kb, adjm, crl, mout);

  // Wo proj -> gout1 ; residual(x f32) + LN1 -> zb (bf16)
  k_gemm<2><<<64 * 8, 256, 0, stream>>>(ctx, wob, 512, 8, nullptr, nullptr, gout1, 512);
  k_resln<<<2048, 256, 0, stream>>>(gout1, x, nullptr, g1, be1, nullptr, zb);
  // FFN1: relu(zb @ W1^T + b1) -> hb
  k_gemm<1><<<64 * 32, 256, 0, stream>>>(zb, w1b, 512, 32, b1, hb, nullptr, 2048);
  // FFN2 -> gout2 ; residual(zb bf16) + LN2 -> out
  k_gemm<2><<<64 * 8, 256, 0, stream>>>(hb, w2b, 2048, 8, b2, nullptr, gout2, 512);
  k_resln<<<2048, 256, 0, stream>>>(gout2, nullptr, zb, g2, be2, out, nullptr);
}

// Round 7
// 244.325 us; speedup vs baseline: 1.9894x; 1.1131x over previous
//
#include <hip/hip_runtime.h>
#include <math.h>
#include <stdint.h>

// GraphTransformerLayer on MI355X (gfx950).
// B=8, N=1024, D=512, H=8, Dh=64, F=2048.
// Round 7: attn_mean -> barrier-free wave-private K streaming (counted vmcnt,
//          no __syncthreads); k_gemm -> 128x128 tile (4x4 frags/wave).

using bf16_t = __bf16;
typedef __attribute__((__ext_vector_type__(8))) __bf16 bf16x8;
typedef __attribute__((__ext_vector_type__(4))) __bf16 bf16x4;
typedef __attribute__((__ext_vector_type__(4))) float  f32x4;

#define DEVI __device__ __forceinline__

DEVI f32x4 mfma16(bf16x8 a, bf16x8 b, f32x4 c) {
  return __builtin_amdgcn_mfma_f32_16x16x32_bf16(a, b, c, 0, 0, 0);
}

// async global->LDS, 16B per lane. dest = wave-uniform base (+ lane*16 by HW).
DEVI void gload_lds16(const void* g, void* l) {
  __builtin_amdgcn_global_load_lds(
      (const __attribute__((address_space(1))) uint32_t*)g,
      (__attribute__((address_space(3))) uint32_t*)l, 16, 0, 0);
}

#define NEGC  (-1.0e9f)
#define EPSC  (1e-5f)

// ---------------- f32 -> bf16 convert (vector4) ----------------
__global__ __launch_bounds__(256) void k_cvt(const float* __restrict__ in,
                                             bf16_t* __restrict__ out, int n4) {
  int i = blockIdx.x * 256 + threadIdx.x;
  if (i < n4) {
    float4 v = ((const float4*)in)[i];
    bf16x4 o = { (__bf16)v.x, (__bf16)v.y, (__bf16)v.z, (__bf16)v.w };
    ((bf16x4*)out)[i] = o;
  }
}

// ---------------- fused weight converts ----------------
__global__ __launch_bounds__(256) void k_cvtw(const float* __restrict__ wq,
                                              const float* __restrict__ wk,
                                              const float* __restrict__ wv,
                                              const float* __restrict__ wo,
                                              const float* __restrict__ w1,
                                              const float* __restrict__ w2,
                                              bf16_t* __restrict__ owq,
                                              bf16_t* __restrict__ owk,
                                              bf16_t* __restrict__ owv,
                                              bf16_t* __restrict__ owo,
                                              bf16_t* __restrict__ ow1,
                                              bf16_t* __restrict__ ow2) {
  int blk = blockIdx.x;
  const float* src; bf16_t* dst; int base;
  if      (blk < 256)  { src = wq; dst = owq; base = blk; }
  else if (blk < 512)  { src = wk; dst = owk; base = blk - 256; }
  else if (blk < 768)  { src = wv; dst = owv; base = blk - 512; }
  else if (blk < 1024) { src = wo; dst = owo; base = blk - 768; }
  else if (blk < 2048) { src = w1; dst = ow1; base = blk - 1024; }
  else                 { src = w2; dst = ow2; base = blk - 2048; }
  int i = base * 256 + threadIdx.x;
  float4 v = ((const float4*)src)[i];
  bf16x4 o = { (__bf16)v.x, (__bf16)v.y, (__bf16)v.z, (__bf16)v.w };
  ((bf16x4*)dst)[i] = o;
}

// ---------------- adjm = mask ? adj : NEG ; rowmax of masked adj ----------------
__global__ __launch_bounds__(256) void k_prep(const float* __restrict__ adj,
                                              const int* __restrict__ msk,
                                              float* __restrict__ adjm,
                                              float* __restrict__ rowmax) {
  int row  = blockIdx.x * 4 + (threadIdx.x >> 6);
  int lane = threadIdx.x & 63;
  float m = -INFINITY;
  for (int i = 0; i < 16; i++) {
    int c = lane + 64 * i;
    size_t idx = (size_t)row * 1024 + c;
    float a = adj[idx];
    bool valid = (msk[idx] != 0);
    adjm[idx] = valid ? a : NEGC;
    if (valid) m = fmaxf(m, a);
  }
  for (int off = 1; off < 64; off <<= 1) m = fmaxf(m, __shfl_xor(m, off));
  if (lane == 0) rowmax[row] = m;
}

// ---------------- tiled GEMM: C[8192 x N] = A[8192 x K] @ B[N x K]^T ----------------
// 128x128 tile, 4 waves (2x2), each wave 64x64 (4x4 fragments). BK=32.
// Double-buffered global_load_lds staging, 16B-block XOR swizzle (blk ^= row&3).
// EPI: 0 = bf16 store with which-routing (which==0 scaled by 0.125 for q),
//      1 = bf16 bias+relu, 2 = f32 (+opt bias).
template<int EPI>
__global__ __launch_bounds__(256) void k_gemm(const bf16_t* __restrict__ A,
                                              const bf16_t* __restrict__ B,
                                              int K, int nbx,
                                              const float* __restrict__ bias,
                                              bf16_t* __restrict__ outb,
                                              float* __restrict__ outf,
                                              int out_ncols) {
  __shared__ bf16_t lA[2][4096];   // [128][32] bf16, 8KB per buf
  __shared__ bf16_t lB[2][4096];   // [128][32] bf16, 8KB per buf
  int bid = blockIdx.x;
  int nb = bid % nbx, mb = bid / nbx;
  int tid = threadIdx.x, wid = tid >> 6, lane = tid & 63;
  int l16 = lane & 15, g = lane >> 4;
  int wr = wid >> 1, wc = wid & 1;
  int rowbase = mb * 128, c0 = nb * 128;

  // staging: wave stages bytes [wid*2048, +2048) of each 8KB tile (2 instrs)
  int dA0 = wid * 2048 + lane * 16;
  int rA0 = dA0 >> 6;                       // row (64B per row), rA1 = rA0+16
  int cbA = ((dA0 >> 4) & 3) ^ (rA0 & 3);   // same for both instrs (+16 rows)
  const bf16_t* Asrc0 = A + (size_t)(rowbase + rA0) * K + cbA * 8;
  const bf16_t* Asrc1 = A + (size_t)(rowbase + rA0 + 16) * K + cbA * 8;
  const bf16_t* Bsrc0 = B + (size_t)(c0 + rA0) * K + cbA * 8;
  const bf16_t* Bsrc1 = B + (size_t)(c0 + rA0 + 16) * K + cbA * 8;

  f32x4 acc[4][4];
#pragma unroll
  for (int m = 0; m < 4; m++)
#pragma unroll
    for (int n = 0; n < 4; n++) acc[m][n] = (f32x4){0.f, 0.f, 0.f, 0.f};

  // prologue stage
  gload_lds16(Asrc0, (char*)&lA[0][0] + wid * 2048);
  gload_lds16(Asrc1, (char*)&lA[0][0] + wid * 2048 + 1024);
  gload_lds16(Bsrc0, (char*)&lB[0][0] + wid * 2048);
  gload_lds16(Bsrc1, (char*)&lB[0][0] + wid * 2048 + 1024);
  __syncthreads();

  for (int k0 = 0; k0 < K; k0 += 32) {
    int buf = (k0 >> 5) & 1;
    if (k0 + 32 < K) {
      gload_lds16(Asrc0 + k0 + 32, (char*)&lA[buf ^ 1][0] + wid * 2048);
      gload_lds16(Asrc1 + k0 + 32, (char*)&lA[buf ^ 1][0] + wid * 2048 + 1024);
      gload_lds16(Bsrc0 + k0 + 32, (char*)&lB[buf ^ 1][0] + wid * 2048);
      gload_lds16(Bsrc1 + k0 + 32, (char*)&lB[buf ^ 1][0] + wid * 2048 + 1024);
    }
    const char* cA = (const char*)&lA[buf][0];
    const char* cB = (const char*)&lB[buf][0];
    bf16x8 af[4], bq[4];
#pragma unroll
    for (int m = 0; m < 4; m++) {
      int row = wr * 64 + m * 16 + l16;
      af[m] = *(const bf16x8*)(cA + row * 64 + ((g ^ (row & 3)) << 4));
    }
#pragma unroll
    for (int n = 0; n < 4; n++) {
      int row = wc * 64 + n * 16 + l16;
      bq[n] = *(const bf16x8*)(cB + row * 64 + ((g ^ (row & 3)) << 4));
    }
#pragma unroll
    for (int m = 0; m < 4; m++)
#pragma unroll
      for (int n = 0; n < 4; n++) acc[m][n] = mfma16(af[m], bq[n], acc[m][n]);
    __syncthreads();   // drains staged loads + read fence
  }

  // epilogue
  int which = c0 / out_ncols;
  int cloc0 = c0 - which * out_ncols;
  size_t obase = (size_t)which * 8192 * out_ncols;
  float osc = (EPI == 0 && which == 0) ? 0.125f : 1.0f;  // q pre-scale
#pragma unroll
  for (int n = 0; n < 4; n++) {
    int col = cloc0 + wc * 64 + n * 16 + l16;
    float bv = (EPI >= 1 && bias) ? bias[col] : 0.f;
#pragma unroll
    for (int m = 0; m < 4; m++)
#pragma unroll
      for (int j = 0; j < 4; j++) {
        int row = rowbase + wr * 64 + m * 16 + g * 4 + j;
        float v = acc[m][n][j] + bv;
        size_t idx = obase + (size_t)row * out_ncols + col;
        if (EPI == 1) outb[idx] = (__bf16)fmaxf(v, 0.f);
        else if (EPI == 0) outb[idx] = (__bf16)(v * osc);
        else outf[idx] = v;
      }
  }
}

// ---------------- residual + LayerNorm (memory-bound): rows of 512 ----------------
__global__ __launch_bounds__(256) void k_resln(const float* __restrict__ gin,
                                               const float* __restrict__ residf,
                                               const bf16_t* __restrict__ residb,
                                               const float* __restrict__ gam,
                                               const float* __restrict__ bet,
                                               float* __restrict__ outf,
                                               bf16_t* __restrict__ outb) {
  int row = blockIdx.x * 4 + (threadIdx.x >> 6);
  int lane = threadIdx.x & 63;
  const float* gp = gin + (size_t)row * 512;
  float4 a0 = ((const float4*)gp)[lane];
  float4 a1 = ((const float4*)gp)[lane + 64];
  if (residf) {
    const float* rp = residf + (size_t)row * 512;
    float4 r0 = ((const float4*)rp)[lane];
    float4 r1 = ((const float4*)rp)[lane + 64];
    a0.x += r0.x; a0.y += r0.y; a0.z += r0.z; a0.w += r0.w;
    a1.x += r1.x; a1.y += r1.y; a1.z += r1.z; a1.w += r1.w;
  } else {
    const bf16_t* rp = residb + (size_t)row * 512;
    bf16x4 r0 = ((const bf16x4*)rp)[lane];
    bf16x4 r1 = ((const bf16x4*)rp)[lane + 64];
    a0.x += (float)r0[0]; a0.y += (float)r0[1]; a0.z += (float)r0[2]; a0.w += (float)r0[3];
    a1.x += (float)r1[0]; a1.y += (float)r1[1]; a1.z += (float)r1[2]; a1.w += (float)r1[3];
  }
  float s = a0.x + a0.y + a0.z + a0.w + a1.x + a1.y + a1.z + a1.w;
  for (int off = 1; off < 64; off <<= 1) s += __shfl_xor(s, off);
  float mu = s * (1.f / 512.f);
  float sq = (a0.x - mu) * (a0.x - mu) + (a0.y - mu) * (a0.y - mu) +
             (a0.z - mu) * (a0.z - mu) + (a0.w - mu) * (a0.w - mu) +
             (a1.x - mu) * (a1.x - mu) + (a1.y - mu) * (a1.y - mu) +
             (a1.z - mu) * (a1.z - mu) + (a1.w - mu) * (a1.w - mu);
  for (int off = 1; off < 64; off <<= 1) sq += __shfl_xor(sq, off);
  float rs = rsqrtf(sq * (1.f / 512.f) + EPSC);

  float4 g0 = ((const float4*)gam)[lane], g1v = ((const float4*)gam)[lane + 64];
  float4 b0 = ((const float4*)bet)[lane], b1v = ((const float4*)bet)[lane + 64];
  float4 o0, o1;
  o0.x = (a0.x - mu) * rs * g0.x + b0.x;  o0.y = (a0.y - mu) * rs * g0.y + b0.y;
  o0.z = (a0.z - mu) * rs * g0.z + b0.z;  o0.w = (a0.w - mu) * rs * g0.w + b0.w;
  o1.x = (a1.x - mu) * rs * g1v.x + b1v.x; o1.y = (a1.y - mu) * rs * g1v.y + b1v.y;
  o1.z = (a1.z - mu) * rs * g1v.z + b1v.z; o1.w = (a1.w - mu) * rs * g1v.w + b1v.w;
  if (outf) {
    float* op = outf + (size_t)row * 512;
    ((float4*)op)[lane] = o0;
    ((float4*)op)[lane + 64] = o1;
  }
  if (outb) {
    bf16_t* op = outb + (size_t)row * 512;
    bf16x4 q0 = { (__bf16)o0.x, (__bf16)o0.y, (__bf16)o0.z, (__bf16)o0.w };
    bf16x4 q1 = { (__bf16)o1.x, (__bf16)o1.y, (__bf16)o1.z, (__bf16)o1.w };
    ((bf16x4*)op)[lane] = q0;
    ((bf16x4*)op)[lane + 64] = q1;
  }
}

// ---------------- v transpose: [B,N,H*64] -> vT [B,H,64,N] ----------------
__global__ __launch_bounds__(256) void k_vtrans(const bf16_t* __restrict__ v,
                                                bf16_t* __restrict__ vT) {
  int bid = blockIdx.x;
  int nt = bid & 15, h = (bid >> 4) & 7, b = bid >> 7;
  __shared__ bf16_t t[64 * 66];
  int tid = threadIdx.x, wid = tid >> 6, lane = tid & 63;
  for (int i = 0; i < 16; i++) {
    int n = wid * 16 + i;
    t[lane * 66 + n] = v[(size_t)(b * 1024 + nt * 64 + n) * 512 + h * 64 + lane];
  }
  __syncthreads();
  for (int i = 0; i < 16; i++) {
    int d = wid * 16 + i;
    vT[(size_t)((b * 8 + h) * 64 + d) * 1024 + nt * 64 + lane] = t[d * 66 + lane];
  }
}

// ---------------- max_n |k[b,h,n,:]| ----------------
__global__ __launch_bounds__(256) void k_knorm(const bf16_t* __restrict__ kk,
                                               float* __restrict__ kmax) {
  int bh = blockIdx.x;
  int b = bh >> 3, h = bh & 7;
  int tid = threadIdx.x;
  float mx = 0.f;
  for (int n = tid; n < 1024; n += 256) {
    const bf16_t* kp = kk + (size_t)(b * 1024 + n) * 512 + h * 64;
    float ss = 0.f;
#pragma unroll
    for (int vv = 0; vv < 8; vv++) {
      bf16x8 kv = *(const bf16x8*)(kp + vv * 8);
#pragma unroll
      for (int e = 0; e < 8; e++) { float f = (float)kv[e]; ss += f * f; }
    }
    mx = fmaxf(mx, ss);
  }
  for (int off = 1; off < 64; off <<= 1) mx = fmaxf(mx, __shfl_xor(mx, off));
  __shared__ float red[4];
  if ((tid & 63) == 0) red[tid >> 6] = mx;
  __syncthreads();
  if (tid == 0) kmax[bh] = sqrtf(fmaxf(fmaxf(red[0], red[1]), fmaxf(red[2], red[3])));
}

// ---------------- score upper bound C[b,h,n] = |q'| * kmax + rowmax(adj) ----------------
__global__ __launch_bounds__(256) void k_cbound(const bf16_t* __restrict__ q,
                                                const float* __restrict__ kmax,
                                                const float* __restrict__ rowmax,
                                                float* __restrict__ Cb) {
  int t = blockIdx.x * 256 + threadIdx.x;  // (b*8+h)*1024 + n
  int b = t >> 13, h = (t >> 10) & 7, n = t & 1023;
  const bf16_t* qp = q + (size_t)(b * 1024 + n) * 512 + h * 64;
  float ss = 0.f;
#pragma unroll
  for (int vv = 0; vv < 8; vv++) {
    bf16x8 kv = *(const bf16x8*)(qp + vv * 8);
#pragma unroll
    for (int e = 0; e < 8; e++) { float f = (float)kv[e]; ss += f * f; }
  }
  float am = rowmax[n];
  Cb[t] = (am < -1e30f) ? 0.f : (sqrtf(ss) * kmax[b * 8 + h] + am);
}

// ---------------- attention partial: un-normalized ctx partial + partial l ----------------
__global__ __launch_bounds__(256) void k_attn_ctx(const bf16_t* __restrict__ q,
                                                  const bf16_t* __restrict__ kk,
                                                  const bf16_t* __restrict__ vT,
                                                  const float* __restrict__ adjm,
                                                  const float* __restrict__ Cb,
                                                  float* __restrict__ lp,
                                                  bf16_t* __restrict__ ctxp0,
                                                  bf16_t* __restrict__ ctxp1) {
  __shared__ bf16_t ldsK[2][4096];
  __shared__ bf16_t ldsV[2][4096];
  __shared__ bf16_t pt[4][16 * 72];
  int bid = blockIdx.x;
  int split = bid & 1, qt = (bid >> 1) & 15, h = (bid >> 5) & 7, b = bid >> 8;
  int tid = threadIdx.x, wid = tid >> 6, lane = tid & 63;
  int l16 = lane & 15, g = lane >> 4;
  int qg0 = qt * 64 + wid * 16;
  bf16_t* ctxp = split ? ctxp1 : ctxp0;
  int kvbase = (b * 8 + h) * 64;

  int d0 = wid * 2048 + lane * 16;
  int row0 = d0 >> 7, row1 = (d0 + 1024) >> 7;
  int cb0 = ((d0 >> 4) & 7) ^ (row0 & 7);
  int cb1 = ((d0 >> 4) & 7) ^ (row1 & 7);
  const bf16_t* ksrc = kk + (size_t)(b * 1024) * 512 + h * 64;
  const bf16_t* vsrc = vT + (size_t)kvbase * 1024;

  auto stage = [&](int buf, int kc0) {
    gload_lds16(ksrc + (size_t)(kc0 + row0) * 512 + cb0 * 8, &ldsK[buf][wid * 1024]);
    gload_lds16(ksrc + (size_t)(kc0 + row1) * 512 + cb1 * 8, &ldsK[buf][wid * 1024 + 512]);
    gload_lds16(vsrc + (size_t)row0 * 1024 + kc0 + cb0 * 8, &ldsV[buf][wid * 1024]);
    gload_lds16(vsrc + (size_t)row1 * 1024 + kc0 + cb1 * 8, &ldsV[buf][wid * 1024 + 512]);
  };

  const bf16_t* qp = q + (size_t)(b * 1024 + qg0 + l16) * 512 + h * 64 + 8 * g;
  bf16x8 aq0 = *(const bf16x8*)qp;
  bf16x8 aq1 = *(const bf16x8*)(qp + 32);

  float Cj[4];
#pragma unroll
  for (int j = 0; j < 4; j++) Cj[j] = Cb[(b * 8 + h) * 1024 + qg0 + g * 4 + j];

  f32x4 cacc[4];
#pragma unroll
  for (int d = 0; d < 4; d++) cacc[d] = (f32x4){0.f, 0.f, 0.f, 0.f};
  float ls[4] = {0.f, 0.f, 0.f, 0.f};
  bf16_t* myp = pt[wid];
  int rph = l16 & 7;

  int ktS = split * 8, ktE = ktS + 8;
  stage(0, ktS * 64);
  __syncthreads();

  for (int kt = ktS; kt < ktE; ++kt) {
    int buf = (kt - ktS) & 1;
    int kc0 = kt * 64;
    int ktn = (kt + 1 < ktE) ? kt + 1 : kt;
    stage(buf ^ 1, ktn * 64);

    float am[4][4];
#pragma unroll
    for (int cg = 0; cg < 4; cg++)
#pragma unroll
      for (int j = 0; j < 4; j++)
        am[cg][j] = adjm[(size_t)(qg0 + g * 4 + j) * 1024 + kc0 + cg * 16 + l16];

    const char* curK = (const char*)ldsK[buf];
    const char* curV = (const char*)ldsV[buf];

#pragma unroll
    for (int cg = 0; cg < 4; cg++) {
      const char* krow = curK + ((cg * 16 + l16) << 7);
      bf16x8 k0 = *(const bf16x8*)(krow + ((g ^ rph) << 4));
      bf16x8 k1 = *(const bf16x8*)(krow + (((g + 4) ^ rph) << 4));
      f32x4 s = (f32x4){0.f, 0.f, 0.f, 0.f};
      s = mfma16(aq0, k0, s);
      s = mfma16(aq1, k1, s);
#pragma unroll
      for (int j = 0; j < 4; j++) {
        float sv = s[j] + am[cg][j];
        float p = __expf(sv - Cj[j]);
        ls[j] += p;
        myp[(g * 4 + j) * 72 + cg * 16 + l16] = (__bf16)p;
      }
    }
#pragma unroll
    for (int half = 0; half < 2; half++) {
      bf16x8 pa = *(const bf16x8*)(myp + l16 * 72 + half * 32 + 8 * g);
#pragma unroll
      for (int dg = 0; dg < 4; dg++) {
        const char* vrow = curV + ((dg * 16 + l16) << 7);
        bf16x8 vv = *(const bf16x8*)(vrow + (((g + half * 4) ^ rph) << 4));
        cacc[dg] = mfma16(pa, vv, cacc[dg]);
      }
    }
    __syncthreads();
  }

#pragma unroll
  for (int j = 0; j < 4; j++)
    for (int off = 1; off < 16; off <<= 1) ls[j] += __shfl_xor(ls[j], off);

#pragma unroll
  for (int dg = 0; dg < 4; dg++)
#pragma unroll
    for (int j = 0; j < 4; j++) {
      int row = qg0 + g * 4 + j;
      ctxp[(size_t)(b * 1024 + row) * 512 + h * 64 + dg * 16 + l16] = (__bf16)cacc[dg][j];
    }
  if (l16 == 0) {
#pragma unroll
    for (int j = 0; j < 4; j++)
      lp[split * 65536 + (b * 8 + h) * 1024 + qg0 + g * 4 + j] = ls[j];
  }
}

// ---------------- combine partials -> ctx bf16, crl = C + ln(l) ----------------
__global__ __launch_bounds__(256) void k_attn_fin(const bf16_t* __restrict__ ctxp0,
                                                  const bf16_t* __restrict__ ctxp1,
                                                  const float* __restrict__ lp,
                                                  const float* __restrict__ Cb,
                                                  bf16_t* __restrict__ ctx,
                                                  float* __restrict__ crl) {
  int t = blockIdx.x * 256 + threadIdx.x;  // 1048576 groups of 4 elems
  int col4 = t & 127, row = t >> 7;
  int b = row >> 10, qq = row & 1023, h = col4 >> 4;
  int li = (b * 8 + h) * 1024 + qq;
  float l = lp[li] + lp[65536 + li];
  float rc = (l > 0.f) ? (1.f / l) : 0.f;
  bf16x4 p0 = ((const bf16x4*)ctxp0)[t];
  bf16x4 p1 = ((const bf16x4*)ctxp1)[t];
  bf16x4 o;
#pragma unroll
  for (int i = 0; i < 4; i++) o[i] = (__bf16)(((float)p0[i] + (float)p1[i]) * rc);
  ((bf16x4*)ctx)[t] = o;
  if ((col4 & 15) == 0)
    crl[li] = (l > 0.f) ? (Cb[li] + __logf(l)) : 1.0e30f;
}

// ---------------- attention mean over heads -> mout (barrier-free) ----------------
// grid 1024: bid = kq(3) | qt(4) | b(3). Wave owns 16q x 128k x 8h; K streamed
// through wave-private 2x4KB LDS bufs (counted vmcnt, no __syncthreads).
// mean = exp(adj) * (1/8) * sum_h exp(s_h - CR_h).
__global__ __launch_bounds__(256, 4) void k_attn_mean(const bf16_t* __restrict__ q,
                                                      const bf16_t* __restrict__ kk,
                                                      const float* __restrict__ adjm,
                                                      const float* __restrict__ crl,
                                                      float* __restrict__ mout) {
  __shared__ bf16_t lds[4][2][2048];   // [wave][buf][4KB]
  int bid = blockIdx.x;
  int kq = bid & 7, qt = (bid >> 3) & 15, b = bid >> 7;
  int tid = threadIdx.x, wid = tid >> 6, lane = tid & 63;
  int l16 = lane & 15, g = lane >> 4;
  int qg0 = qt * 64 + wid * 16;
  int kbase = kq * 128;
  int rl = lane >> 3;                 // 0..7 (row-within-8 for staging)
  int cb = (lane & 7) ^ rl;           // pre-swizzled 16B src block
  const bf16_t* ksrc = kk + (size_t)(b * 1024 + kbase) * 512;

  // stage chunk t (= h*4 + c): K rows [kbase + c*32, +32) x dh[ h*64, +64 )
  auto stage = [&](int t) {
    int h = t >> 2, c = t & 3;
    char* dst = (char*)&lds[wid][t & 1][0];
    const bf16_t* sp = ksrc + (size_t)(c * 32 + rl) * 512 + h * 64 + cb * 8;
#pragma unroll
    for (int i = 0; i < 4; i++)
      gload_lds16(sp + (size_t)i * 8 * 512, dst + i * 1024);
  };

  f32x4 macc[8];
#pragma unroll
  for (int kg = 0; kg < 8; kg++) macc[kg] = (f32x4){0.f, 0.f, 0.f, 0.f};

  stage(0);

  for (int h = 0; h < 8; h++) {
    const bf16_t* qp = q + (size_t)(b * 1024 + qg0 + l16) * 512 + h * 64 + 8 * g;
    bf16x8 aq0 = *(const bf16x8*)qp;
    bf16x8 aq1 = *(const bf16x8*)(qp + 32);
    f32x4 CR = *(const f32x4*)(crl + (b * 8 + h) * 1024 + qg0 + g * 4);
#pragma unroll
    for (int c = 0; c < 4; c++) {
      int t = h * 4 + c;
      __builtin_amdgcn_sched_barrier(0);
      if (t < 31) {
        stage(t + 1);
        __builtin_amdgcn_sched_barrier(0);
        asm volatile("s_waitcnt vmcnt(4)" ::: "memory");  // current buf landed
      } else {
        asm volatile("s_waitcnt vmcnt(0)" ::: "memory");
      }
      __builtin_amdgcn_sched_barrier(0);
      const char* cK = (const char*)&lds[wid][t & 1][0];
#pragma unroll
      for (int cg = 0; cg < 2; cg++) {
        const char* krow = cK + ((cg * 16 + l16) << 7);
        bf16x8 k0 = *(const bf16x8*)(krow + ((g ^ (l16 & 7)) << 4));
        bf16x8 k1 = *(const bf16x8*)(krow + (((g + 4) ^ (l16 & 7)) << 4));
        f32x4 s = (f32x4){0.f, 0.f, 0.f, 0.f};
        s = mfma16(aq0, k0, s);
        s = mfma16(aq1, k1, s);
        int kg = c * 2 + cg;
#pragma unroll
        for (int j = 0; j < 4; j++)
          macc[kg][j] += __expf(s[j] - CR[j]);
      }
    }
  }

  // epilogue: multiply by exp(adj)/8 and store
#pragma unroll
  for (int kg = 0; kg < 8; kg++)
#pragma unroll
    for (int j = 0; j < 4; j++) {
      size_t off = (size_t)(qg0 + g * 4 + j) * 1024 + kbase + kg * 16 + l16;
      mout[(size_t)b * 1048576 + off] = macc[kg][j] * __expf(adjm[off]) * 0.125f;
    }
}

extern "C" void kernel_launch(void* const* d_in, const int* in_sizes, int n_in,
                              void* d_out, int out_size, void* d_ws, size_t ws_size,
                              hipStream_t stream) {
  (void)in_sizes; (void)n_in; (void)out_size; (void)ws_size;
  const float* x   = (const float*)d_in[0];
  const float* adj = (const float*)d_in[1];
  const int*   msk = (const int*)d_in[2];
  const float* Wq  = (const float*)d_in[3];
  const float* Wk  = (const float*)d_in[4];
  const float* Wv  = (const float*)d_in[5];
  const float* Wo  = (const float*)d_in[6];
  const float* W1  = (const float*)d_in[7];
  const float* b1  = (const float*)d_in[8];
  const float* W2  = (const float*)d_in[9];
  const float* b2  = (const float*)d_in[10];
  const float* g1  = (const float*)d_in[11];
  const float* be1 = (const float*)d_in[12];
  const float* g2  = (const float*)d_in[13];
  const float* be2 = (const float*)d_in[14];

  float* out  = (float*)d_out;
  float* mout = out + (size_t)8 * 1024 * 512;

  char* ws = (char*)d_ws;
  const size_t MB = 1024 * 1024;
  bf16_t* wqb = (bf16_t*)(ws);
  bf16_t* wkb = (bf16_t*)(ws + 512 * 1024);
  bf16_t* wvb = (bf16_t*)(ws + 1 * MB);
  bf16_t* wob = (bf16_t*)(ws + 3 * MB / 2);
  bf16_t* w1b = (bf16_t*)(ws + 2 * MB);
  bf16_t* w2b = (bf16_t*)(ws + 4 * MB);
  float*  Cb   = (float*)(ws + 6 * MB);              // 256 KB
  float*  crl  = (float*)(ws + 6 * MB + 256 * 1024); // 256 KB (C + ln l)
  float*  amax = (float*)(ws + 6 * MB + 512 * 1024); // 4 KB
  float*  kmax = (float*)(ws + 6 * MB + 768 * 1024); // 256 B
  float*  lp   = (float*)(ws + 7 * MB);              // 512 KB
  bf16_t* xb   = (bf16_t*)(ws + 8 * MB);   // 8-16: x bf16; then ctx; then zb
  bf16_t* ctx  = xb;
  bf16_t* zb   = xb;
  bf16_t* qb   = (bf16_t*)(ws + 16 * MB);  // 16-24
  bf16_t* kb   = (bf16_t*)(ws + 24 * MB);  // 24-32
  bf16_t* vb   = (bf16_t*)(ws + 32 * MB);  // 32-40 (dead after vtrans)
  bf16_t* ctxp1 = vb;
  bf16_t* vT   = (bf16_t*)(ws + 40 * MB);  // 40-48
  bf16_t* ctxp0 = (bf16_t*)(ws + 48 * MB); // 48-56
  float*  gout1 = (float*)(ws + 16 * MB);  // 16-32 f32 (wo-gemm -> resln1)
  bf16_t* hb    = (bf16_t*)(ws + 16 * MB); // 16-48 bf16 (ffn1 -> ffn2)
  float*  gout2 = (float*)(ws + 48 * MB);  // 48-64 f32 (ffn2 -> resln2)
  float*  adjm  = (float*)(ws + 72 * MB);  // 72-76

  // converts
  k_cvt<<<4096, 256, 0, stream>>>(x, xb, 1048576);
  k_cvtw<<<3072, 256, 0, stream>>>(Wq, Wk, Wv, Wo, W1, W2,
                                   wqb, wkb, wvb, wob, w1b, w2b);

  k_prep<<<256, 256, 0, stream>>>(adj, msk, adjm, amax);

  // QKV: one GEMM, N=1536 (wq|wk|wv contiguous); q output pre-scaled by 0.125
  k_gemm<0><<<64 * 12, 256, 0, stream>>>(xb, wqb, 512, 12, nullptr, qb, nullptr, 512);
  k_vtrans<<<1024, 256, 0, stream>>>(vb, vT);
  k_knorm<<<64, 256, 0, stream>>>(kb, kmax);
  k_cbound<<<256, 256, 0, stream>>>(qb, kmax, amax, Cb);

  // attention: partials (k-split x2), combine (-> ctx, crl), mean
  k_attn_ctx<<<2048, 256, 0, stream>>>(qb, kb, vT, adjm, Cb, lp, ctxp0, ctxp1);
  k_attn_fin<<<4096, 256, 0, stream>>>(ctxp0, ctxp1, lp, Cb, ctx, crl);
  k_attn_mean<<<1024, 256, 0, stream>>>(qb, kb, adjm, crl, mout);

  // Wo proj -> gout1 ; residual(x f32) + LN1 -> zb (bf16)
  k_gemm<2><<<64 * 4, 256, 0, stream>>>(ctx, wob, 512, 4, nullptr, nullptr, gout1, 512);
  k_resln<<<2048, 256, 0, stream>>>(gout1, x, nullptr, g1, be1, nullptr, zb);
  // FFN1: relu(zb @ W1^T + b1) -> hb
  k_gemm<1><<<64 * 16, 256, 0, stream>>>(zb, w1b, 512, 16, b1, hb, nullptr, 2048);
  // FFN2 -> gout2 ; residual(zb bf16) + LN2 -> out
  k_gemm<2><<<64 * 4, 256, 0, stream>>>(hb, w2b, 2048, 4, b2, nullptr, gout2, 512);
  k_resln<<<2048, 256, 0, stream>>>(gout2, nullptr, zb, g2, be2, out, nullptr);
}